// Round 1
// baseline (20364.915 us; speedup 1.0000x reference)
//
#include <hip/hip_runtime.h>
#include <math.h>

// ---------------------------------------------------------------- helpers
__device__ __forceinline__ float sigmoid_(float x) { return 1.f / (1.f + __expf(-x)); }
__device__ __forceinline__ float tanh_(float x) {
  x = fminf(fmaxf(x, -30.f), 30.f);
  float e = __expf(2.f * x);
  return (e - 1.f) / (e + 1.f);
}
__device__ __forceinline__ float softplus_(float x) {
  return (x > 15.f) ? x : log1pf(__expf(x));
}

// Per-thread GEMM tile: node = lane (64 nodes/block), wave wq owns CPT columns.
// A: LDS, layout [K][LDA], read A[k*LDA+lane] (lane-consecutive -> conflict-free).
// WT: row-major [cols][ldw]; address wave-uniform -> s_load path.
template<int CPT, int LDA>
__device__ __forceinline__ void gemm_tile(float* acc, const float* A, int K,
                                          const float* WT, int ldw, int lane, int wq)
{
  for (int k0 = 0; k0 < K; k0 += 8) {
    float a[8];
#pragma unroll
    for (int i = 0; i < 8; ++i) a[i] = A[(k0 + i) * LDA + lane];
#pragma unroll
    for (int u = 0; u < CPT; ++u) {
      const float* wr = WT + (size_t)(wq * CPT + u) * ldw + k0;
#pragma unroll
      for (int i = 0; i < 8; ++i) acc[u] = fmaf(a[i], wr[i], acc[u]);
    }
  }
}

// ---------------------------------------------------------------- LSTM (fused 2 layers, 20 steps)
__device__ __forceinline__ void lstm_epi(const float* acc, float* c, float (*h)[64],
    const float* __restrict__ bih, const float* __restrict__ bhh, int lane, int wq)
{
#pragma unroll
  for (int u = 0; u < 32; ++u) {
    const int col = wq * 32 + u;
    float gi = acc[u]      + bih[col]       + bhh[col];
    float gf = acc[32 + u] + bih[128 + col] + bhh[128 + col];
    float gg = acc[64 + u] + bih[256 + col] + bhh[256 + col];
    float go = acc[96 + u] + bih[384 + col] + bhh[384 + col];
    float ci = sigmoid_(gf) * c[u] + sigmoid_(gi) * tanh_(gg);
    c[u] = ci;
    h[col][lane] = sigmoid_(go) * tanh_(ci);
  }
}

__global__ __launch_bounds__(256, 2) void lstm_fused(
    const float* __restrict__ seq,
    const float* __restrict__ Wih0, const float* __restrict__ Whh0,
    const float* __restrict__ bih0, const float* __restrict__ bhh0,
    const float* __restrict__ Wih1, const float* __restrict__ Whh1,
    const float* __restrict__ bih1, const float* __restrict__ bhh1,
    float* __restrict__ hfinal, int n)
{
  __shared__ float h0[128][64];   // [unit][node]
  __shared__ float h1[128][64];
  const int lane = threadIdx.x & 63;
  const int wq = __builtin_amdgcn_readfirstlane(threadIdx.x >> 6);
  const int node = blockIdx.x * 64 + lane;
  const int nld = min(node, n - 1);

  float c0[32], c1[32], acc[128];
#pragma unroll
  for (int u = 0; u < 32; ++u) { c0[u] = 0.f; c1[u] = 0.f; }
  for (int i = threadIdx.x; i < 128 * 64; i += 256) {
    (&h0[0][0])[i] = 0.f; (&h1[0][0])[i] = 0.f;
  }
  __syncthreads();

  for (int t = 0; t < 20; ++t) {
    // x_t in registers (each wave loads its own copy; L2-cached)
    float xr[16];
    const float* xp = seq + (size_t)nld * 320 + t * 16;
#pragma unroll
    for (int i = 0; i < 16; i += 4) {
      float4 v = *(const float4*)(xp + i);
      xr[i] = v.x; xr[i + 1] = v.y; xr[i + 2] = v.z; xr[i + 3] = v.w;
    }
    // ---- layer 0: gates = x@Wih0^T + h0@Whh0^T ----
#pragma unroll
    for (int i = 0; i < 128; ++i) acc[i] = 0.f;
#pragma unroll
    for (int g = 0; g < 4; ++g) {
#pragma unroll
      for (int u = 0; u < 32; ++u) {
        const float* wr = Wih0 + (size_t)(g * 128 + wq * 32 + u) * 16;
#pragma unroll
        for (int i = 0; i < 16; ++i) acc[g * 32 + u] = fmaf(xr[i], wr[i], acc[g * 32 + u]);
      }
      gemm_tile<32, 64>(acc + g * 32, &h0[0][0], 128, Whh0 + (size_t)(g * 128) * 128, 128, lane, wq);
    }
    __syncthreads();                       // all reads of h0 done
    lstm_epi(acc, c0, h0, bih0, bhh0, lane, wq);
    __syncthreads();                       // new h0 visible
    // ---- layer 1: gates = h0@Wih1^T + h1@Whh1^T ----
#pragma unroll
    for (int i = 0; i < 128; ++i) acc[i] = 0.f;
#pragma unroll
    for (int g = 0; g < 4; ++g) {
      gemm_tile<32, 64>(acc + g * 32, &h0[0][0], 128, Wih1 + (size_t)(g * 128) * 128, 128, lane, wq);
      gemm_tile<32, 64>(acc + g * 32, &h1[0][0], 128, Whh1 + (size_t)(g * 128) * 128, 128, lane, wq);
    }
    __syncthreads();
    lstm_epi(acc, c1, h1, bih1, bhh1, lane, wq);
    __syncthreads();
  }

  if (node < n) {
#pragma unroll
    for (int u = 0; u < 32; ++u)
      hfinal[(size_t)node * 128 + wq * 32 + u] = h1[wq * 32 + u][lane];
  }
}

// ---------------------------------------------------------------- generic node GEMM: out = act(x @ WT^T + b)
template<int KDIM, int COLS, bool RELU, bool BIAS>
__global__ __launch_bounds__(256, 4) void ngemm(
    const float* __restrict__ xin, const float* __restrict__ WT,
    const float* __restrict__ b, float* __restrict__ out, int n)
{
  __shared__ float A[KDIM][65];
  const int lane = threadIdx.x & 63;
  const int wq = __builtin_amdgcn_readfirstlane(threadIdx.x >> 6);
  const int node = blockIdx.x * 64 + lane;

  for (int i = threadIdx.x; i < 64 * KDIM; i += 256) {
    int nn = i / KDIM, k = i % KDIM;
    int g = min(blockIdx.x * 64 + nn, n - 1);
    A[k][nn] = xin[(size_t)g * KDIM + k];
  }
  __syncthreads();

  constexpr int CPT = COLS / 4;
  float acc[CPT];
#pragma unroll
  for (int u = 0; u < CPT; ++u) acc[u] = 0.f;
  gemm_tile<CPT, 65>(acc, &A[0][0], KDIM, WT, KDIM, lane, wq);

  if (node < n) {
#pragma unroll
    for (int u = 0; u < CPT; ++u) {
      int col = wq * CPT + u;
      float v = acc[u];
      if (BIAS) v += b[col];
      if (RELU) v = fmaxf(v, 0.f);
      out[(size_t)node * COLS + col] = v;
    }
  }
}

// ---------------------------------------------------------------- small utility kernels
__global__ void transpose_k(const float* __restrict__ s, float* __restrict__ d, int R, int C) {
  int i = blockIdx.x * 256 + threadIdx.x;
  if (i < R * C) { int r = i / C, c = i % C; d[(size_t)c * R + r] = s[i]; }
}

__global__ void deg_count(const int* __restrict__ dst, float* __restrict__ deg, int ne, int n) {
  int i = blockIdx.x * 256 + threadIdx.x;
  if (i < ne) {
    int d = dst[i]; d = min(max(d, 0), n - 1);
    atomicAdd(deg + d, 1.f);
  }
}

__global__ void dinv_k(const float* __restrict__ deg, float* __restrict__ dinv, int n) {
  int i = blockIdx.x * 256 + threadIdx.x;
  if (i < n) dinv[i] = rsqrtf(deg[i] + 1.f);   // +1 self-loop
}

__global__ void selfinit_k(const float* __restrict__ y, const float* __restrict__ dinv,
                           float* __restrict__ o, int n) {
  int i = blockIdx.x * 256 + threadIdx.x;
  if (i < n * 128) { int nd = i >> 7; float dv = dinv[nd]; o[i] = dv * dv * y[i]; }
}

__global__ void biasrelu_k(const float* __restrict__ o, const float* __restrict__ b,
                           float* __restrict__ x, int n) {
  int i = blockIdx.x * 256 + threadIdx.x;
  if (i < n * 128) x[i] = fmaxf(o[i] + b[i & 127], 0.f);
}

__global__ void scatter_k(const float* __restrict__ y, const int* __restrict__ src,
                          const int* __restrict__ dst, const float* __restrict__ dinv,
                          float* __restrict__ o, int ne, int n) {
  int e = blockIdx.x * 8 + (threadIdx.x >> 5);
  if (e >= ne) return;
  int l = threadIdx.x & 31;
  int s = min(max(src[e], 0), n - 1);
  int d = min(max(dst[e], 0), n - 1);
  float nr = dinv[s] * dinv[d];
  float4 v = *(const float4*)(y + (size_t)s * 128 + l * 4);
  float* od = o + (size_t)d * 128 + l * 4;
  atomicAdd(od + 0, nr * v.x); atomicAdd(od + 1, nr * v.y);
  atomicAdd(od + 2, nr * v.z); atomicAdd(od + 3, nr * v.w);
}

// ---------------------------------------------------------------- heads
__global__ __launch_bounds__(256, 2) void node_heads(
    const float* __restrict__ x,
    const float* __restrict__ cW1T, const float* __restrict__ cb1,
    const float* __restrict__ cW2T, const float* __restrict__ cb2,
    const float* __restrict__ uW1T, const float* __restrict__ ub1,
    const float* __restrict__ uW2,  const float* __restrict__ ub2,
    float* __restrict__ cls, float* __restrict__ unc, int n)
{
  int node = blockIdx.x * 256 + threadIdx.x;
  int nld = min(node, n - 1);
  const float* xp = x + (size_t)nld * 128;
  float hc[64], hu[64];
#pragma unroll
  for (int j = 0; j < 64; ++j) { hc[j] = cb1[j]; hu[j] = ub1[j]; }
  for (int k0 = 0; k0 < 128; k0 += 8) {
    float xk[8];
    *(float4*)&xk[0] = *(const float4*)(xp + k0);
    *(float4*)&xk[4] = *(const float4*)(xp + k0 + 4);
#pragma unroll
    for (int j = 0; j < 64; ++j) {
      const float* cw = cW1T + (size_t)j * 128 + k0;
      const float* uw = uW1T + (size_t)j * 128 + k0;
#pragma unroll
      for (int i = 0; i < 8; ++i) {
        hc[j] = fmaf(xk[i], cw[i], hc[j]);
        hu[j] = fmaf(xk[i], uw[i], hu[j]);
      }
    }
  }
  float vc0 = cb2[0], vc1 = cb2[1], vc2 = cb2[2], vc3 = cb2[3];
  float ua = ub2[0];
#pragma unroll
  for (int j = 0; j < 64; ++j) {
    float hcr = fmaxf(hc[j], 0.f), hur = fmaxf(hu[j], 0.f);
    vc0 = fmaf(hcr, cW2T[0 * 64 + j], vc0);
    vc1 = fmaf(hcr, cW2T[1 * 64 + j], vc1);
    vc2 = fmaf(hcr, cW2T[2 * 64 + j], vc2);
    vc3 = fmaf(hcr, cW2T[3 * 64 + j], vc3);
    ua  = fmaf(hur, uW2[j], ua);
  }
  if (node < n) {
    float4 vo; vo.x = vc0; vo.y = vc1; vo.z = vc2; vo.w = vc3;
    *(float4*)(cls + (size_t)node * 4) = vo;
    unc[node] = softplus_(ua);
  }
}

// edge head: h1 = relu(P[src]+Q[dst]+b1); h2 = relu(h1@W2+b2); ep = sigmoid(h2@W3+b3)
__global__ __launch_bounds__(256, 2) void edge_head(
    const float* __restrict__ P, const float* __restrict__ Q,
    const int* __restrict__ src, const int* __restrict__ dst,
    const float* __restrict__ b1,
    const float* __restrict__ eW2T, const float* __restrict__ b2,
    const float* __restrict__ eW3, const float* __restrict__ b3,
    float* __restrict__ ep, int ne, int n)
{
  __shared__ float H1[128][66];
  __shared__ float H2[64][64];
  const int lane = threadIdx.x & 63;
  const int wq = __builtin_amdgcn_readfirstlane(threadIdx.x >> 6);
  const int e0 = blockIdx.x * 64;
  {
    int el = threadIdx.x >> 2, q = threadIdx.x & 3;
    int e = min(e0 + el, ne - 1);
    int s = min(max(src[e], 0), n - 1);
    int d = min(max(dst[e], 0), n - 1);
    const float* pr = P + (size_t)s * 128 + q * 32;
    const float* qr = Q + (size_t)d * 128 + q * 32;
#pragma unroll
    for (int i = 0; i < 32; i += 4) {
      float4 a = *(const float4*)(pr + i);
      float4 c = *(const float4*)(qr + i);
      int jb = q * 32 + i;
      H1[jb + 0][el] = fmaxf(a.x + c.x + b1[jb + 0], 0.f);
      H1[jb + 1][el] = fmaxf(a.y + c.y + b1[jb + 1], 0.f);
      H1[jb + 2][el] = fmaxf(a.z + c.z + b1[jb + 2], 0.f);
      H1[jb + 3][el] = fmaxf(a.w + c.w + b1[jb + 3], 0.f);
    }
  }
  __syncthreads();
  float acc[16];
#pragma unroll
  for (int u = 0; u < 16; ++u) acc[u] = 0.f;
  gemm_tile<16, 66>(acc, &H1[0][0], 128, eW2T, 128, lane, wq);
#pragma unroll
  for (int u = 0; u < 16; ++u) {
    int col = wq * 16 + u;
    H2[col][lane] = fmaxf(acc[u] + b2[col], 0.f);
  }
  __syncthreads();
  if (wq == 0) {
    float a3 = b3[0];
    for (int k = 0; k < 64; ++k) a3 = fmaf(H2[k][lane], eW3[k], a3);
    int e = e0 + lane;
    if (e < ne) ep[e] = 1.f / (1.f + __expf(-a3));
  }
}

// ---------------------------------------------------------------- host
extern "C" void kernel_launch(void* const* d_in, const int* in_sizes, int n_in,
                              void* d_out, int out_size, void* d_ws, size_t ws_size,
                              hipStream_t stream)
{
  const float* seq   = (const float*)d_in[0];
  const int*   eidx  = (const int*)d_in[1];
  const float* Wih0  = (const float*)d_in[2];
  const float* Whh0  = (const float*)d_in[3];
  const float* bih0  = (const float*)d_in[4];
  const float* bhh0  = (const float*)d_in[5];
  const float* Wih1  = (const float*)d_in[6];
  const float* Whh1  = (const float*)d_in[7];
  const float* bih1  = (const float*)d_in[8];
  const float* bhh1  = (const float*)d_in[9];
  const float* encW1 = (const float*)d_in[10];
  const float* encb1 = (const float*)d_in[11];
  const float* encW2 = (const float*)d_in[12];
  const float* encb2 = (const float*)d_in[13];
  const float* gW0   = (const float*)d_in[14];
  const float* gb0   = (const float*)d_in[15];
  const float* gW1   = (const float*)d_in[16];
  const float* gb1   = (const float*)d_in[17];
  const float* gW2   = (const float*)d_in[18];
  const float* gb2   = (const float*)d_in[19];
  const float* eW1   = (const float*)d_in[20];
  const float* eb1   = (const float*)d_in[21];
  const float* eW2   = (const float*)d_in[22];
  const float* eb2   = (const float*)d_in[23];
  const float* eW3   = (const float*)d_in[24];
  const float* eb3   = (const float*)d_in[25];
  const float* cW1   = (const float*)d_in[26];
  const float* cb1   = (const float*)d_in[27];
  const float* cW2   = (const float*)d_in[28];
  const float* cb2   = (const float*)d_in[29];
  const float* uW1   = (const float*)d_in[30];
  const float* ub1   = (const float*)d_in[31];
  const float* uW2   = (const float*)d_in[32];
  const float* ub2   = (const float*)d_in[33];

  const int n  = in_sizes[0] / 320;     // 50000
  const int ne = in_sizes[1] / 2;       // 800000
  const int* src = eidx;
  const int* dst = eidx + ne;

  // workspace carve-up
  char* ws = (char*)d_ws;
  size_t off = 0;
  auto alloc = [&](size_t elems) -> float* {
    float* p = (float*)(ws + off);
    off += ((elems * 4 + 255) & ~(size_t)255);
    return p;
  };
  const size_t nb = (size_t)n * 128;
  float* B1     = alloc(nb);        // hf, later P
  float* B2     = alloc(nb);        // t1 / y / Q
  float* B3     = alloc(nb);        // oacc
  float* B4     = alloc(nb);        // x (gcn activations)
  float* latent = alloc((size_t)n * 64);
  float* deg    = alloc(n);
  float* dinv   = alloc(n);
  float* encW1T = alloc(128 * 128);
  float* encW2T = alloc(64 * 128);
  float* gW0T   = alloc(128 * 64);
  float* gW1T   = alloc(128 * 128);
  float* gW2T   = alloc(128 * 128);
  float* eW1tT  = alloc(128 * 128);
  float* eW1bT  = alloc(128 * 128);
  float* eW2T   = alloc(64 * 128);
  float* cW1T   = alloc(64 * 128);
  float* cW2T   = alloc(4 * 64);
  float* uW1T   = alloc(64 * 128);
  (void)ws_size; (void)n_in; (void)out_size;

  float* xout = (float*)d_out;                    // [n][128]
  float* ep   = xout + nb;                        // [ne]
  float* cls  = ep + ne;                          // [n][4]
  float* unc  = cls + (size_t)n * 4;              // [n]

  auto T = [&](const float* s, float* d, int R, int C) {
    transpose_k<<<dim3((R * C + 255) / 256), dim3(256), 0, stream>>>(s, d, R, C);
  };
  T(encW1, encW1T, 128, 128);
  T(encW2, encW2T, 128, 64);
  T(gW0,   gW0T,   64, 128);
  T(gW1,   gW1T,   128, 128);
  T(gW2,   gW2T,   128, 128);
  T(eW1,            eW1tT, 128, 128);
  T(eW1 + 128*128,  eW1bT, 128, 128);
  T(eW2,   eW2T,   128, 64);
  T(cW1,   cW1T,   128, 64);
  T(cW2,   cW2T,   64, 4);
  T(uW1,   uW1T,   128, 64);

  // degree / norm
  hipMemsetAsync(deg, 0, (size_t)n * 4, stream);
  deg_count<<<dim3((ne + 255) / 256), dim3(256), 0, stream>>>(dst, deg, ne, n);
  dinv_k<<<dim3((n + 255) / 256), dim3(256), 0, stream>>>(deg, dinv, n);

  const int nblk = (n + 63) / 64;
  // LSTM -> B1
  lstm_fused<<<dim3(nblk), dim3(256), 0, stream>>>(
      seq, Wih0, Whh0, bih0, bhh0, Wih1, Whh1, bih1, bhh1, B1, n);

  // encoder: B1 -> B2 -> latent
  ngemm<128, 128, true,  true ><<<dim3(nblk), dim3(256), 0, stream>>>(B1, encW1T, encb1, B2, n);
  ngemm<128, 64,  false, true ><<<dim3(nblk), dim3(256), 0, stream>>>(B2, encW2T, encb2, latent, n);

  const int eblk32 = (ne + 7) / 8;
  const int elblk  = (n * 128 + 255) / 256;
  // GCN layer 0: latent(64) -> B4
  ngemm<64, 128, false, false><<<dim3(nblk), dim3(256), 0, stream>>>(latent, gW0T, nullptr, B2, n);
  selfinit_k<<<dim3(elblk), dim3(256), 0, stream>>>(B2, dinv, B3, n);
  scatter_k<<<dim3(eblk32), dim3(256), 0, stream>>>(B2, src, dst, dinv, B3, ne, n);
  biasrelu_k<<<dim3(elblk), dim3(256), 0, stream>>>(B3, gb0, B4, n);
  // GCN layer 1: B4 -> B4
  ngemm<128, 128, false, false><<<dim3(nblk), dim3(256), 0, stream>>>(B4, gW1T, nullptr, B2, n);
  selfinit_k<<<dim3(elblk), dim3(256), 0, stream>>>(B2, dinv, B3, n);
  scatter_k<<<dim3(eblk32), dim3(256), 0, stream>>>(B2, src, dst, dinv, B3, ne, n);
  biasrelu_k<<<dim3(elblk), dim3(256), 0, stream>>>(B3, gb1, B4, n);
  // GCN layer 2: B4 -> xout (d_out)
  ngemm<128, 128, false, false><<<dim3(nblk), dim3(256), 0, stream>>>(B4, gW2T, nullptr, B2, n);
  selfinit_k<<<dim3(elblk), dim3(256), 0, stream>>>(B2, dinv, B3, n);
  scatter_k<<<dim3(eblk32), dim3(256), 0, stream>>>(B2, src, dst, dinv, B3, ne, n);
  biasrelu_k<<<dim3(elblk), dim3(256), 0, stream>>>(B3, gb2, xout, n);

  // edge head precompute: P = x@W1_top, Q = x@W1_bot
  ngemm<128, 128, false, false><<<dim3(nblk), dim3(256), 0, stream>>>(xout, eW1tT, nullptr, B1, n);
  ngemm<128, 128, false, false><<<dim3(nblk), dim3(256), 0, stream>>>(xout, eW1bT, nullptr, B2, n);
  edge_head<<<dim3((ne + 63) / 64), dim3(256), 0, stream>>>(
      B1, B2, src, dst, eb1, eW2T, eb2, eW3, eb3, ep, ne, n);

  node_heads<<<dim3((n + 255) / 256), dim3(256), 0, stream>>>(
      xout, cW1T, cb1, cW2T, cb2, uW1T, ub1, uW2, ub2, cls, unc, n);
}

// Round 2
// 7441.064 us; speedup vs baseline: 2.7368x; 2.7368x over previous
//
#include <hip/hip_runtime.h>
#include <math.h>

typedef float f32x4 __attribute__((ext_vector_type(4)));
typedef short s16x8 __attribute__((ext_vector_type(8)));

// ---------------------------------------------------------------- helpers
__device__ __forceinline__ float sigmoid_(float x) { return 1.f / (1.f + __expf(-x)); }
__device__ __forceinline__ float tanh_(float x) {
  x = fminf(fmaxf(x, -30.f), 30.f);
  float e = __expf(2.f * x);
  return (e - 1.f) / (e + 1.f);
}
__device__ __forceinline__ float softplus_(float x) {
  return (x > 15.f) ? x : log1pf(__expf(x));
}
__device__ __forceinline__ unsigned short f2bf(float f) {  // RNE fp32->bf16
  unsigned u = __float_as_uint(f);
  u += 0x7fffu + ((u >> 16) & 1u);
  return (unsigned short)(u >> 16);
}

// Per-thread GEMM tile: node = lane (64 nodes/block), wave wq owns CPT columns.
template<int CPT, int LDA>
__device__ __forceinline__ void gemm_tile(float* acc, const float* A, int K,
                                          const float* WT, int ldw, int lane, int wq)
{
  for (int k0 = 0; k0 < K; k0 += 8) {
    float a[8];
#pragma unroll
    for (int i = 0; i < 8; ++i) a[i] = A[(k0 + i) * LDA + lane];
#pragma unroll
    for (int u = 0; u < CPT; ++u) {
      const float* wr = WT + (size_t)(wq * CPT + u) * ldw + k0;
#pragma unroll
      for (int i = 0; i < 8; ++i) acc[u] = fmaf(a[i], wr[i], acc[u]);
    }
  }
}

// ---------------------------------------------------------------- LSTM weight prep
// Wp0: [20 chunks][512 cols][8] bf16 ; k<16 -> Wih0, 16..31 -> 0 (pad), 32..159 -> Whh0
// Wp1: [32 chunks][512 cols][8] bf16 ; k<128 -> Wih1, else Whh1
__global__ void prep_lstm_w(const float* __restrict__ Wih0, const float* __restrict__ Whh0,
                            const float* __restrict__ Wih1, const float* __restrict__ Whh1,
                            const float* __restrict__ bih0, const float* __restrict__ bhh0,
                            const float* __restrict__ bih1, const float* __restrict__ bhh1,
                            unsigned short* __restrict__ Wp0, unsigned short* __restrict__ Wp1,
                            float* __restrict__ bs0, float* __restrict__ bs1)
{
  int idx = blockIdx.x * 256 + threadIdx.x;
  if (idx < 20 * 512 * 8) {
    int c = idx >> 12, rem = idx & 4095;
    int col = rem >> 3, e = rem & 7;
    int k = c * 8 + e;
    float v = 0.f;
    if (k < 16) v = Wih0[col * 16 + k];
    else if (k >= 32) v = Whh0[col * 128 + (k - 32)];
    Wp0[idx] = f2bf(v);
  }
  int i1 = idx - 20 * 512 * 8;
  if (i1 >= 0 && i1 < 32 * 512 * 8) {
    int c = i1 >> 12, rem = i1 & 4095;
    int col = rem >> 3, e = rem & 7;
    int k = c * 8 + e;
    float v = (k < 128) ? Wih1[col * 128 + k] : Whh1[col * 128 + (k - 128)];
    Wp1[i1] = f2bf(v);
  }
  int i2 = idx - 52 * 512 * 8;
  if (i2 >= 0 && i2 < 512) bs0[i2] = bih0[i2] + bhh0[i2];
  int i3 = i2 - 512;
  if (i3 >= 0 && i3 < 512) bs1[i3] = bih1[i3] + bhh1[i3];
}

// ---------------------------------------------------------------- LSTM (MFMA, fused 2 layers)
// Block: 512 threads (8 waves) x 64 nodes. LDS A-chunks [chunk][node][8] bf16:
//   chunks 0..3: x_t (16) + zero pad (16); 4..19: h0 (128); 20..35: h1 (128).
// Wave wq owns cols {g*128 + wq*16 + lane%16 : g=0..3} (i,f,g,o for same unit set).
__device__ __forceinline__ void lstm_epi_m(const f32x4 (&acc)[4][4], f32x4 (&cs)[4],
    const float (&bs)[4], unsigned short* __restrict__ lds, int uoff, int kq,
    int nodebase, float* __restrict__ hf, int u, int n, bool last)
{
#pragma unroll
  for (int m = 0; m < 4; ++m) {
#pragma unroll
    for (int r = 0; r < 4; ++r) {
      float gi = acc[m][0][r] + bs[0];
      float gf = acc[m][1][r] + bs[1];
      float gg = acc[m][2][r] + bs[2];
      float go = acc[m][3][r] + bs[3];
      float c = sigmoid_(gf) * cs[m][r] + sigmoid_(gi) * tanh_(gg);
      cs[m][r] = c;
      float h = sigmoid_(go) * tanh_(c);
      int node = m * 16 + kq * 4 + r;
      lds[uoff + node * 8] = f2bf(h);
      if (last) {
        int gn = nodebase + node;
        if (gn < n) hf[(size_t)gn * 128 + u] = h;
      }
    }
  }
}

__global__ __launch_bounds__(512, 1) void lstm_mfma(
    const float* __restrict__ seq,
    const unsigned short* __restrict__ Wp0, const unsigned short* __restrict__ Wp1,
    const float* __restrict__ bs0, const float* __restrict__ bs1,
    float* __restrict__ hfinal, int n)
{
  __shared__ __align__(16) unsigned short Abuf[36 * 512];
  const int tid = threadIdx.x;
  const int l = tid & 63;
  const int wq = __builtin_amdgcn_readfirstlane(tid >> 6);
  const int kq = l >> 4;                    // k-chunk subgroup within a k-step
  const int la = (l & 15) * 8;              // A lane elem offset (node part)
  const int colu = wq * 16 + (l & 15);      // unit index u (0..127)
  const int nodebase = blockIdx.x * 64;

  // zero pad chunks (2,3) + h0 + h1 chunks (4..35)
  for (int i = tid; i < 34 * 512; i += 512) Abuf[2 * 512 + i] = 0;

  float bsr0[4], bsr1[4];
#pragma unroll
  for (int g = 0; g < 4; ++g) {
    bsr0[g] = bs0[g * 128 + colu];
    bsr1[g] = bs1[g * 128 + colu];
  }
  const int uoff0 = (4 + (colu >> 3)) * 512 + (colu & 7);    // h0 write slot
  const int uoff1 = (20 + (colu >> 3)) * 512 + (colu & 7);   // h1 write slot

  const f32x4 zero4 = {0.f, 0.f, 0.f, 0.f};
  f32x4 c0[4], c1[4];
#pragma unroll
  for (int m = 0; m < 4; ++m) { c0[m] = zero4; c1[m] = zero4; }

  for (int t = 0; t < 20; ++t) {
    // ---- stage x_t -> chunks 0,1 (bf16) ----
    if (tid < 256) {
      int nd = tid >> 2, q = tid & 3;
      int gnode = min(nodebase + nd, n - 1);
      float4 v = *(const float4*)(seq + (size_t)gnode * 320 + t * 16 + q * 4);
      unsigned d0 = (unsigned)f2bf(v.x) | ((unsigned)f2bf(v.y) << 16);
      unsigned d1 = (unsigned)f2bf(v.z) | ((unsigned)f2bf(v.w) << 16);
      unsigned* dst = (unsigned*)&Abuf[(q >> 1) * 512 + nd * 8 + (q & 1) * 4];
      dst[0] = d0; dst[1] = d1;
    }
    __syncthreads();   // x staged; h0/h1 writes from prev step visible

    // ---- layer 0: gates = [x|pad|h0] @ Wp0  (K=160, 5 k-steps) ----
    f32x4 acc[4][4];
#pragma unroll
    for (int m = 0; m < 4; ++m)
#pragma unroll
      for (int g = 0; g < 4; ++g) acc[m][g] = zero4;
#pragma unroll
    for (int kc = 0; kc < 5; ++kc) {
      s16x8 av[4];
#pragma unroll
      for (int m = 0; m < 4; ++m)
        av[m] = *(const s16x8*)&Abuf[(kc * 4 + kq) * 512 + m * 128 + la];
#pragma unroll
      for (int g = 0; g < 4; ++g) {
        s16x8 bv = *(const s16x8*)&Wp0[(size_t)(kc * 4 + kq) * 4096 + (g * 128 + colu) * 8];
#pragma unroll
        for (int m = 0; m < 4; ++m)
          acc[m][g] = __builtin_amdgcn_mfma_f32_16x16x32_bf16(av[m], bv, acc[m][g], 0, 0, 0);
      }
    }
    __syncthreads();   // all reads of h0 done
    lstm_epi_m(acc, c0, bsr0, Abuf, uoff0, kq, nodebase, hfinal, colu, n, false);
    __syncthreads();   // new h0 visible

    // ---- layer 1: gates = [h0|h1] @ Wp1  (K=256, 8 k-steps) ----
#pragma unroll
    for (int m = 0; m < 4; ++m)
#pragma unroll
      for (int g = 0; g < 4; ++g) acc[m][g] = zero4;
#pragma unroll
    for (int kc = 0; kc < 8; ++kc) {
      s16x8 av[4];
#pragma unroll
      for (int m = 0; m < 4; ++m)
        av[m] = *(const s16x8*)&Abuf[(4 + kc * 4 + kq) * 512 + m * 128 + la];
#pragma unroll
      for (int g = 0; g < 4; ++g) {
        s16x8 bv = *(const s16x8*)&Wp1[(size_t)(kc * 4 + kq) * 4096 + (g * 128 + colu) * 8];
#pragma unroll
        for (int m = 0; m < 4; ++m)
          acc[m][g] = __builtin_amdgcn_mfma_f32_16x16x32_bf16(av[m], bv, acc[m][g], 0, 0, 0);
      }
    }
    __syncthreads();   // all reads of h0/h1 done
    lstm_epi_m(acc, c1, bsr1, Abuf, uoff1, kq, nodebase, hfinal, colu, n, t == 19);
    // next iteration's staging barrier makes h1 writes visible
  }
}

// ---------------------------------------------------------------- generic node GEMM
template<int KDIM, int COLS, bool RELU, bool BIAS>
__global__ __launch_bounds__(256, 4) void ngemm(
    const float* __restrict__ xin, const float* __restrict__ WT,
    const float* __restrict__ b, float* __restrict__ out, int n)
{
  __shared__ float A[KDIM][65];
  const int lane = threadIdx.x & 63;
  const int wq = __builtin_amdgcn_readfirstlane(threadIdx.x >> 6);
  const int node = blockIdx.x * 64 + lane;

  for (int i = threadIdx.x; i < 64 * KDIM; i += 256) {
    int nn = i / KDIM, k = i % KDIM;
    int g = min(blockIdx.x * 64 + nn, n - 1);
    A[k][nn] = xin[(size_t)g * KDIM + k];
  }
  __syncthreads();

  constexpr int CPT = COLS / 4;
  float acc[CPT];
#pragma unroll
  for (int u = 0; u < CPT; ++u) acc[u] = 0.f;
  gemm_tile<CPT, 65>(acc, &A[0][0], KDIM, WT, KDIM, lane, wq);

  if (node < n) {
#pragma unroll
    for (int u = 0; u < CPT; ++u) {
      int col = wq * CPT + u;
      float v = acc[u];
      if (BIAS) v += b[col];
      if (RELU) v = fmaxf(v, 0.f);
      out[(size_t)node * COLS + col] = v;
    }
  }
}

// ---------------------------------------------------------------- small utility kernels
__global__ void transpose_k(const float* __restrict__ s, float* __restrict__ d, int R, int C) {
  int i = blockIdx.x * 256 + threadIdx.x;
  if (i < R * C) { int r = i / C, c = i % C; d[(size_t)c * R + r] = s[i]; }
}

__global__ void deg_count(const int* __restrict__ dst, float* __restrict__ deg, int ne, int n) {
  int i = blockIdx.x * 256 + threadIdx.x;
  if (i < ne) {
    int d = dst[i]; d = min(max(d, 0), n - 1);
    atomicAdd(deg + d, 1.f);
  }
}

__global__ void dinv_k(const float* __restrict__ deg, float* __restrict__ dinv, int n) {
  int i = blockIdx.x * 256 + threadIdx.x;
  if (i < n) dinv[i] = rsqrtf(deg[i] + 1.f);   // +1 self-loop
}

__global__ void selfinit_k(const float* __restrict__ y, const float* __restrict__ dinv,
                           float* __restrict__ o, int n) {
  int i = blockIdx.x * 256 + threadIdx.x;
  if (i < n * 128) { int nd = i >> 7; float dv = dinv[nd]; o[i] = dv * dv * y[i]; }
}

__global__ void biasrelu_k(const float* __restrict__ o, const float* __restrict__ b,
                           float* __restrict__ x, int n) {
  int i = blockIdx.x * 256 + threadIdx.x;
  if (i < n * 128) x[i] = fmaxf(o[i] + b[i & 127], 0.f);
}

__global__ void scatter_k(const float* __restrict__ y, const int* __restrict__ src,
                          const int* __restrict__ dst, const float* __restrict__ dinv,
                          float* __restrict__ o, int ne, int n) {
  int e = blockIdx.x * 8 + (threadIdx.x >> 5);
  if (e >= ne) return;
  int l = threadIdx.x & 31;
  int s = min(max(src[e], 0), n - 1);
  int d = min(max(dst[e], 0), n - 1);
  float nr = dinv[s] * dinv[d];
  float4 v = *(const float4*)(y + (size_t)s * 128 + l * 4);
  float* od = o + (size_t)d * 128 + l * 4;
  atomicAdd(od + 0, nr * v.x); atomicAdd(od + 1, nr * v.y);
  atomicAdd(od + 2, nr * v.z); atomicAdd(od + 3, nr * v.w);
}

// ---------------------------------------------------------------- heads
__global__ __launch_bounds__(256, 2) void node_heads(
    const float* __restrict__ x,
    const float* __restrict__ cW1T, const float* __restrict__ cb1,
    const float* __restrict__ cW2T, const float* __restrict__ cb2,
    const float* __restrict__ uW1T, const float* __restrict__ ub1,
    const float* __restrict__ uW2,  const float* __restrict__ ub2,
    float* __restrict__ cls, float* __restrict__ unc, int n)
{
  int node = blockIdx.x * 256 + threadIdx.x;
  int nld = min(node, n - 1);
  const float* xp = x + (size_t)nld * 128;
  float hc[64], hu[64];
#pragma unroll
  for (int j = 0; j < 64; ++j) { hc[j] = cb1[j]; hu[j] = ub1[j]; }
  for (int k0 = 0; k0 < 128; k0 += 8) {
    float xk[8];
    *(float4*)&xk[0] = *(const float4*)(xp + k0);
    *(float4*)&xk[4] = *(const float4*)(xp + k0 + 4);
#pragma unroll
    for (int j = 0; j < 64; ++j) {
      const float* cw = cW1T + (size_t)j * 128 + k0;
      const float* uw = uW1T + (size_t)j * 128 + k0;
#pragma unroll
      for (int i = 0; i < 8; ++i) {
        hc[j] = fmaf(xk[i], cw[i], hc[j]);
        hu[j] = fmaf(xk[i], uw[i], hu[j]);
      }
    }
  }
  float vc0 = cb2[0], vc1 = cb2[1], vc2 = cb2[2], vc3 = cb2[3];
  float ua = ub2[0];
#pragma unroll
  for (int j = 0; j < 64; ++j) {
    float hcr = fmaxf(hc[j], 0.f), hur = fmaxf(hu[j], 0.f);
    vc0 = fmaf(hcr, cW2T[0 * 64 + j], vc0);
    vc1 = fmaf(hcr, cW2T[1 * 64 + j], vc1);
    vc2 = fmaf(hcr, cW2T[2 * 64 + j], vc2);
    vc3 = fmaf(hcr, cW2T[3 * 64 + j], vc3);
    ua  = fmaf(hur, uW2[j], ua);
  }
  if (node < n) {
    float4 vo; vo.x = vc0; vo.y = vc1; vo.z = vc2; vo.w = vc3;
    *(float4*)(cls + (size_t)node * 4) = vo;
    unc[node] = softplus_(ua);
  }
}

__global__ __launch_bounds__(256, 2) void edge_head(
    const float* __restrict__ P, const float* __restrict__ Q,
    const int* __restrict__ src, const int* __restrict__ dst,
    const float* __restrict__ b1,
    const float* __restrict__ eW2T, const float* __restrict__ b2,
    const float* __restrict__ eW3, const float* __restrict__ b3,
    float* __restrict__ ep, int ne, int n)
{
  __shared__ float H1[128][66];
  __shared__ float H2[64][64];
  const int lane = threadIdx.x & 63;
  const int wq = __builtin_amdgcn_readfirstlane(threadIdx.x >> 6);
  const int e0 = blockIdx.x * 64;
  {
    int el = threadIdx.x >> 2, q = threadIdx.x & 3;
    int e = min(e0 + el, ne - 1);
    int s = min(max(src[e], 0), n - 1);
    int d = min(max(dst[e], 0), n - 1);
    const float* pr = P + (size_t)s * 128 + q * 32;
    const float* qr = Q + (size_t)d * 128 + q * 32;
#pragma unroll
    for (int i = 0; i < 32; i += 4) {
      float4 a = *(const float4*)(pr + i);
      float4 c = *(const float4*)(qr + i);
      int jb = q * 32 + i;
      H1[jb + 0][el] = fmaxf(a.x + c.x + b1[jb + 0], 0.f);
      H1[jb + 1][el] = fmaxf(a.y + c.y + b1[jb + 1], 0.f);
      H1[jb + 2][el] = fmaxf(a.z + c.z + b1[jb + 2], 0.f);
      H1[jb + 3][el] = fmaxf(a.w + c.w + b1[jb + 3], 0.f);
    }
  }
  __syncthreads();
  float acc[16];
#pragma unroll
  for (int u = 0; u < 16; ++u) acc[u] = 0.f;
  gemm_tile<16, 66>(acc, &H1[0][0], 128, eW2T, 128, lane, wq);
#pragma unroll
  for (int u = 0; u < 16; ++u) {
    int col = wq * 16 + u;
    H2[col][lane] = fmaxf(acc[u] + b2[col], 0.f);
  }
  __syncthreads();
  if (wq == 0) {
    float a3 = b3[0];
    for (int k = 0; k < 64; ++k) a3 = fmaf(H2[k][lane], eW3[k], a3);
    int e = e0 + lane;
    if (e < ne) ep[e] = 1.f / (1.f + __expf(-a3));
  }
}

// ---------------------------------------------------------------- host
extern "C" void kernel_launch(void* const* d_in, const int* in_sizes, int n_in,
                              void* d_out, int out_size, void* d_ws, size_t ws_size,
                              hipStream_t stream)
{
  const float* seq   = (const float*)d_in[0];
  const int*   eidx  = (const int*)d_in[1];
  const float* Wih0  = (const float*)d_in[2];
  const float* Whh0  = (const float*)d_in[3];
  const float* bih0  = (const float*)d_in[4];
  const float* bhh0  = (const float*)d_in[5];
  const float* Wih1  = (const float*)d_in[6];
  const float* Whh1  = (const float*)d_in[7];
  const float* bih1  = (const float*)d_in[8];
  const float* bhh1  = (const float*)d_in[9];
  const float* encW1 = (const float*)d_in[10];
  const float* encb1 = (const float*)d_in[11];
  const float* encW2 = (const float*)d_in[12];
  const float* encb2 = (const float*)d_in[13];
  const float* gW0   = (const float*)d_in[14];
  const float* gb0   = (const float*)d_in[15];
  const float* gW1   = (const float*)d_in[16];
  const float* gb1   = (const float*)d_in[17];
  const float* gW2   = (const float*)d_in[18];
  const float* gb2   = (const float*)d_in[19];
  const float* eW1   = (const float*)d_in[20];
  const float* eb1   = (const float*)d_in[21];
  const float* eW2   = (const float*)d_in[22];
  const float* eb2   = (const float*)d_in[23];
  const float* eW3   = (const float*)d_in[24];
  const float* eb3   = (const float*)d_in[25];
  const float* cW1   = (const float*)d_in[26];
  const float* cb1   = (const float*)d_in[27];
  const float* cW2   = (const float*)d_in[28];
  const float* cb2   = (const float*)d_in[29];
  const float* uW1   = (const float*)d_in[30];
  const float* ub1   = (const float*)d_in[31];
  const float* uW2   = (const float*)d_in[32];
  const float* ub2   = (const float*)d_in[33];

  const int n  = in_sizes[0] / 320;     // 50000
  const int ne = in_sizes[1] / 2;       // 800000
  const int* src = eidx;
  const int* dst = eidx + ne;

  char* ws = (char*)d_ws;
  size_t off = 0;
  auto alloc = [&](size_t elems) -> float* {
    float* p = (float*)(ws + off);
    off += ((elems * 4 + 255) & ~(size_t)255);
    return p;
  };
  const size_t nb = (size_t)n * 128;
  float* B1     = alloc(nb);        // hf, later P
  float* B2     = alloc(nb);        // t1 / y / Q
  float* B3     = alloc(nb);        // oacc
  float* B4     = alloc(nb);        // x (gcn activations)
  float* latent = alloc((size_t)n * 64);
  float* deg    = alloc(n);
  float* dinv   = alloc(n);
  float* encW1T = alloc(128 * 128);
  float* encW2T = alloc(64 * 128);
  float* gW0T   = alloc(128 * 64);
  float* gW1T   = alloc(128 * 128);
  float* gW2T   = alloc(128 * 128);
  float* eW1tT  = alloc(128 * 128);
  float* eW1bT  = alloc(128 * 128);
  float* eW2T   = alloc(64 * 128);
  float* cW1T   = alloc(64 * 128);
  float* cW2T   = alloc(4 * 64);
  float* uW1T   = alloc(64 * 128);
  unsigned short* Wp0 = (unsigned short*)alloc(20 * 512 * 8 / 2);
  unsigned short* Wp1 = (unsigned short*)alloc(32 * 512 * 8 / 2);
  float* bsum0  = alloc(512);
  float* bsum1  = alloc(512);
  (void)ws_size; (void)n_in; (void)out_size;

  float* xout = (float*)d_out;                    // [n][128]
  float* ep   = xout + nb;                        // [ne]
  float* cls  = ep + ne;                          // [n][4]
  float* unc  = cls + (size_t)n * 4;              // [n]

  auto T = [&](const float* s, float* d, int R, int C) {
    transpose_k<<<dim3((R * C + 255) / 256), dim3(256), 0, stream>>>(s, d, R, C);
  };
  T(encW1, encW1T, 128, 128);
  T(encW2, encW2T, 128, 64);
  T(gW0,   gW0T,   64, 128);
  T(gW1,   gW1T,   128, 128);
  T(gW2,   gW2T,   128, 128);
  T(eW1,            eW1tT, 128, 128);
  T(eW1 + 128*128,  eW1bT, 128, 128);
  T(eW2,   eW2T,   128, 64);
  T(cW1,   cW1T,   128, 64);
  T(cW2,   cW2T,   64, 4);
  T(uW1,   uW1T,   128, 64);

  // LSTM weight packing (bf16 fragment order) + combined biases
  prep_lstm_w<<<dim3((52 * 512 * 8 + 1024 + 255) / 256), dim3(256), 0, stream>>>(
      Wih0, Whh0, Wih1, Whh1, bih0, bhh0, bih1, bhh1, Wp0, Wp1, bsum0, bsum1);

  // degree / norm
  hipMemsetAsync(deg, 0, (size_t)n * 4, stream);
  deg_count<<<dim3((ne + 255) / 256), dim3(256), 0, stream>>>(dst, deg, ne, n);
  dinv_k<<<dim3((n + 255) / 256), dim3(256), 0, stream>>>(deg, dinv, n);

  const int nblk = (n + 63) / 64;
  // LSTM -> B1 (MFMA path)
  lstm_mfma<<<dim3(nblk), dim3(512), 0, stream>>>(seq, Wp0, Wp1, bsum0, bsum1, B1, n);

  // encoder: B1 -> B2 -> latent
  ngemm<128, 128, true,  true ><<<dim3(nblk), dim3(256), 0, stream>>>(B1, encW1T, encb1, B2, n);
  ngemm<128, 64,  false, true ><<<dim3(nblk), dim3(256), 0, stream>>>(B2, encW2T, encb2, latent, n);

  const int eblk32 = (ne + 7) / 8;
  const int elblk  = (n * 128 + 255) / 256;
  // GCN layer 0: latent(64) -> B4
  ngemm<64, 128, false, false><<<dim3(nblk), dim3(256), 0, stream>>>(latent, gW0T, nullptr, B2, n);
  selfinit_k<<<dim3(elblk), dim3(256), 0, stream>>>(B2, dinv, B3, n);
  scatter_k<<<dim3(eblk32), dim3(256), 0, stream>>>(B2, src, dst, dinv, B3, ne, n);
  biasrelu_k<<<dim3(elblk), dim3(256), 0, stream>>>(B3, gb0, B4, n);
  // GCN layer 1
  ngemm<128, 128, false, false><<<dim3(nblk), dim3(256), 0, stream>>>(B4, gW1T, nullptr, B2, n);
  selfinit_k<<<dim3(elblk), dim3(256), 0, stream>>>(B2, dinv, B3, n);
  scatter_k<<<dim3(eblk32), dim3(256), 0, stream>>>(B2, src, dst, dinv, B3, ne, n);
  biasrelu_k<<<dim3(elblk), dim3(256), 0, stream>>>(B3, gb1, B4, n);
  // GCN layer 2 -> xout
  ngemm<128, 128, false, false><<<dim3(nblk), dim3(256), 0, stream>>>(B4, gW2T, nullptr, B2, n);
  selfinit_k<<<dim3(elblk), dim3(256), 0, stream>>>(B2, dinv, B3, n);
  scatter_k<<<dim3(eblk32), dim3(256), 0, stream>>>(B2, src, dst, dinv, B3, ne, n);
  biasrelu_k<<<dim3(elblk), dim3(256), 0, stream>>>(B3, gb2, xout, n);

  // edge head precompute: P = x@W1_top, Q = x@W1_bot
  ngemm<128, 128, false, false><<<dim3(nblk), dim3(256), 0, stream>>>(xout, eW1tT, nullptr, B1, n);
  ngemm<128, 128, false, false><<<dim3(nblk), dim3(256), 0, stream>>>(xout, eW1bT, nullptr, B2, n);
  edge_head<<<dim3((ne + 63) / 64), dim3(256), 0, stream>>>(
      B1, B2, src, dst, eb1, eW2T, eb2, eW3, eb3, ep, ne, n);

  node_heads<<<dim3((n + 255) / 256), dim3(256), 0, stream>>>(
      xout, cW1T, cb1, cW2T, cb2, uW1T, ub1, uW2, ub2, cls, unc, n);
}

// Round 3
// 3679.743 us; speedup vs baseline: 5.5343x; 2.0222x over previous
//
#include <hip/hip_runtime.h>
#include <math.h>

typedef float f32x4 __attribute__((ext_vector_type(4)));
typedef short s16x8 __attribute__((ext_vector_type(8)));

// ---------------------------------------------------------------- helpers
__device__ __forceinline__ float sigmoid_(float x) { return 1.f / (1.f + __expf(-x)); }
__device__ __forceinline__ float tanh_(float x) {
  x = fminf(fmaxf(x, -30.f), 30.f);
  float e = __expf(2.f * x);
  return (e - 1.f) / (e + 1.f);
}
__device__ __forceinline__ float softplus_(float x) {
  return (x > 15.f) ? x : log1pf(__expf(x));
}
__device__ __forceinline__ unsigned short f2bf(float f) {  // RNE fp32->bf16
  unsigned u = __float_as_uint(f);
  u += 0x7fffu + ((u >> 16) & 1u);
  return (unsigned short)(u >> 16);
}

// Per-thread GEMM tile: node = lane (64 nodes/block), wave wq owns CPT columns.
template<int CPT, int LDA>
__device__ __forceinline__ void gemm_tile(float* acc, const float* A, int K,
                                          const float* WT, int ldw, int lane, int wq)
{
  for (int k0 = 0; k0 < K; k0 += 8) {
    float a[8];
#pragma unroll
    for (int i = 0; i < 8; ++i) a[i] = A[(k0 + i) * LDA + lane];
#pragma unroll
    for (int u = 0; u < CPT; ++u) {
      const float* wr = WT + (size_t)(wq * CPT + u) * ldw + k0;
#pragma unroll
      for (int i = 0; i < 8; ++i) acc[u] = fmaf(a[i], wr[i], acc[u]);
    }
  }
}

// ---------------------------------------------------------------- LSTM weight prep
// Wp0: [20 chunks][512 cols][8] bf16 ; k<16 -> Wih0, 16..31 -> 0 (pad), 32..159 -> Whh0
// Wp1: [32 chunks][512 cols][8] bf16 ; k<128 -> Wih1, else Whh1
__global__ void prep_lstm_w(const float* __restrict__ Wih0, const float* __restrict__ Whh0,
                            const float* __restrict__ Wih1, const float* __restrict__ Whh1,
                            const float* __restrict__ bih0, const float* __restrict__ bhh0,
                            const float* __restrict__ bih1, const float* __restrict__ bhh1,
                            unsigned short* __restrict__ Wp0, unsigned short* __restrict__ Wp1,
                            float* __restrict__ bs0, float* __restrict__ bs1)
{
  int idx = blockIdx.x * 256 + threadIdx.x;
  if (idx < 20 * 512 * 8) {
    int c = idx >> 12, rem = idx & 4095;
    int col = rem >> 3, e = rem & 7;
    int k = c * 8 + e;
    float v = 0.f;
    if (k < 16) v = Wih0[col * 16 + k];
    else if (k >= 32) v = Whh0[col * 128 + (k - 32)];
    Wp0[idx] = f2bf(v);
  }
  int i1 = idx - 20 * 512 * 8;
  if (i1 >= 0 && i1 < 32 * 512 * 8) {
    int c = i1 >> 12, rem = i1 & 4095;
    int col = rem >> 3, e = rem & 7;
    int k = c * 8 + e;
    float v = (k < 128) ? Wih1[col * 128 + k] : Whh1[col * 128 + (k - 128)];
    Wp1[i1] = f2bf(v);
  }
  int i2 = idx - 52 * 512 * 8;
  if (i2 >= 0 && i2 < 512) bs0[i2] = bih0[i2] + bhh0[i2];
  int i3 = i2 - 512;
  if (i3 >= 0 && i3 < 512) bs1[i3] = bih1[i3] + bhh1[i3];
}

// ---------------------------------------------------------------- LSTM (MFMA, reg-resident weights, persistent)
__device__ __forceinline__ void lstm_epi_m(const f32x4 (&acc)[4][4], f32x4 (&cs)[4],
    const float (&bs)[4], unsigned short* __restrict__ lds, int uoff, int kq,
    int nodebase, float* __restrict__ hf, int u, int n, bool last)
{
#pragma unroll
  for (int m = 0; m < 4; ++m) {
#pragma unroll
    for (int r = 0; r < 4; ++r) {
      float gi = acc[m][0][r] + bs[0];
      float gf = acc[m][1][r] + bs[1];
      float gg = acc[m][2][r] + bs[2];
      float go = acc[m][3][r] + bs[3];
      float c = sigmoid_(gf) * cs[m][r] + sigmoid_(gi) * tanh_(gg);
      cs[m][r] = c;
      float h = sigmoid_(go) * tanh_(c);
      int node = m * 16 + kq * 4 + r;
      lds[uoff + node * 8] = f2bf(h);
      if (last) {
        int gn = nodebase + node;
        if (gn < n) hf[(size_t)gn * 128 + u] = h;
      }
    }
  }
}

__global__ __launch_bounds__(512, 1) void lstm_reg(
    const float* __restrict__ seq,
    const unsigned short* __restrict__ Wp0, const unsigned short* __restrict__ Wp1,
    const float* __restrict__ bs0, const float* __restrict__ bs1,
    float* __restrict__ hfinal, int n, int ntiles)
{
  __shared__ __align__(16) unsigned short Abuf[36 * 512];
  const int tid = threadIdx.x;
  const int l = tid & 63;
  const int wq = __builtin_amdgcn_readfirstlane(tid >> 6);
  const int kq = l >> 4;
  const int la = (l & 15) * 8;
  const int colu = wq * 16 + (l & 15);
  const int uoff0 = (4 + (colu >> 3)) * 512 + (colu & 7);
  const int uoff1 = (20 + (colu >> 3)) * 512 + (colu & 7);

  // ---- load all B-fragments into registers (once) ----
  s16x8 b0[5][4], b1[8][4];
#pragma unroll
  for (int kc = 0; kc < 5; ++kc)
#pragma unroll
    for (int g = 0; g < 4; ++g)
      b0[kc][g] = *(const s16x8*)&Wp0[(size_t)(kc * 4 + kq) * 4096 + (g * 128 + colu) * 8];
#pragma unroll
  for (int kc = 0; kc < 8; ++kc)
#pragma unroll
    for (int g = 0; g < 4; ++g)
      b1[kc][g] = *(const s16x8*)&Wp1[(size_t)(kc * 4 + kq) * 4096 + (g * 128 + colu) * 8];

  float bsr0[4], bsr1[4];
#pragma unroll
  for (int g = 0; g < 4; ++g) {
    bsr0[g] = bs0[g * 128 + colu];
    bsr1[g] = bs1[g * 128 + colu];
  }
  const f32x4 zero4 = {0.f, 0.f, 0.f, 0.f};

  for (int tile = blockIdx.x; tile < ntiles; tile += gridDim.x) {
    const int nodebase = tile * 64;
    const int nld = min(nodebase + (tid >> 2), n - 1);
    // zero pad chunks (2,3) + h0 + h1 chunks (4..35)
    for (int i = tid; i < 34 * 512; i += 512) Abuf[2 * 512 + i] = 0;
    // stage x(0)
    if (tid < 256) {
      int nd = tid >> 2, q = tid & 3;
      float4 v = *(const float4*)(seq + (size_t)nld * 320 + q * 4);
      unsigned d0 = (unsigned)f2bf(v.x) | ((unsigned)f2bf(v.y) << 16);
      unsigned d1 = (unsigned)f2bf(v.z) | ((unsigned)f2bf(v.w) << 16);
      unsigned* dst = (unsigned*)&Abuf[(q >> 1) * 512 + nd * 8 + (q & 1) * 4];
      dst[0] = d0; dst[1] = d1;
    }
    f32x4 c0[4], c1[4];
#pragma unroll
    for (int m = 0; m < 4; ++m) { c0[m] = zero4; c1[m] = zero4; }
    __syncthreads();

    for (int t = 0; t < 20; ++t) {
      // prefetch x(t+1) into regs (consumed after bar1; latency hidden under L0 MFMA)
      float4 xnext;
      const bool ldx = (t < 19) && (tid < 256);
      if (ldx) xnext = *(const float4*)(seq + (size_t)nld * 320 + (t + 1) * 16 + (tid & 3) * 4);

      // ---- layer 0: gates = [x|pad|h0] @ Wp0 (K=160) ----
      f32x4 acc[4][4];
#pragma unroll
      for (int m = 0; m < 4; ++m)
#pragma unroll
        for (int g = 0; g < 4; ++g) acc[m][g] = zero4;
#pragma unroll
      for (int kc = 0; kc < 5; ++kc) {
        s16x8 av[4];
#pragma unroll
        for (int m = 0; m < 4; ++m)
          av[m] = *(const s16x8*)&Abuf[(kc * 4 + kq) * 512 + m * 128 + la];
#pragma unroll
        for (int g = 0; g < 4; ++g)
#pragma unroll
          for (int m = 0; m < 4; ++m)
            acc[m][g] = __builtin_amdgcn_mfma_f32_16x16x32_bf16(av[m], b0[kc][g], acc[m][g], 0, 0, 0);
      }
      __syncthreads();   // bar1: L0 reads done
      lstm_epi_m(acc, c0, bsr0, Abuf, uoff0, kq, nodebase, hfinal, colu, n, false);
      if (ldx) {
        int nd = tid >> 2, q = tid & 3;
        unsigned d0 = (unsigned)f2bf(xnext.x) | ((unsigned)f2bf(xnext.y) << 16);
        unsigned d1 = (unsigned)f2bf(xnext.z) | ((unsigned)f2bf(xnext.w) << 16);
        unsigned* dst = (unsigned*)&Abuf[(q >> 1) * 512 + nd * 8 + (q & 1) * 4];
        dst[0] = d0; dst[1] = d1;
      }
      __syncthreads();   // bar2: h0 + x(t+1) visible

      // ---- layer 1: gates = [h0|h1] @ Wp1 (K=256) ----
#pragma unroll
      for (int m = 0; m < 4; ++m)
#pragma unroll
        for (int g = 0; g < 4; ++g) acc[m][g] = zero4;
#pragma unroll
      for (int kc = 0; kc < 8; ++kc) {
        s16x8 av[4];
#pragma unroll
        for (int m = 0; m < 4; ++m)
          av[m] = *(const s16x8*)&Abuf[(4 + kc * 4 + kq) * 512 + m * 128 + la];
#pragma unroll
        for (int g = 0; g < 4; ++g)
#pragma unroll
          for (int m = 0; m < 4; ++m)
            acc[m][g] = __builtin_amdgcn_mfma_f32_16x16x32_bf16(av[m], b1[kc][g], acc[m][g], 0, 0, 0);
      }
      __syncthreads();   // bar3: L1 reads done
      lstm_epi_m(acc, c1, bsr1, Abuf, uoff1, kq, nodebase, hfinal, colu, n, t == 19);
      __syncthreads();   // bar4: h1 visible for next t / next tile
    }
  }
}

// ---------------------------------------------------------------- generic node GEMM
template<int KDIM, int COLS, bool RELU, bool BIAS>
__global__ __launch_bounds__(256, 4) void ngemm(
    const float* __restrict__ xin, const float* __restrict__ WT,
    const float* __restrict__ b, float* __restrict__ out, int n)
{
  __shared__ float A[KDIM][65];
  const int lane = threadIdx.x & 63;
  const int wq = __builtin_amdgcn_readfirstlane(threadIdx.x >> 6);
  const int node = blockIdx.x * 64 + lane;

  for (int i = threadIdx.x; i < 64 * KDIM; i += 256) {
    int nn = i / KDIM, k = i % KDIM;
    int g = min(blockIdx.x * 64 + nn, n - 1);
    A[k][nn] = xin[(size_t)g * KDIM + k];
  }
  __syncthreads();

  constexpr int CPT = COLS / 4;
  float acc[CPT];
#pragma unroll
  for (int u = 0; u < CPT; ++u) acc[u] = 0.f;
  gemm_tile<CPT, 65>(acc, &A[0][0], KDIM, WT, KDIM, lane, wq);

  if (node < n) {
#pragma unroll
    for (int u = 0; u < CPT; ++u) {
      int col = wq * CPT + u;
      float v = acc[u];
      if (BIAS) v += b[col];
      if (RELU) v = fmaxf(v, 0.f);
      out[(size_t)node * COLS + col] = v;
    }
  }
}

// ---------------------------------------------------------------- small utility kernels
__global__ void transpose_k(const float* __restrict__ s, float* __restrict__ d, int R, int C) {
  int i = blockIdx.x * 256 + threadIdx.x;
  if (i < R * C) { int r = i / C, c = i % C; d[(size_t)c * R + r] = s[i]; }
}

__global__ void deg_count(const int* __restrict__ dst, float* __restrict__ deg, int ne, int n) {
  int i = blockIdx.x * 256 + threadIdx.x;
  if (i < ne) {
    int d = dst[i]; d = min(max(d, 0), n - 1);
    atomicAdd(deg + d, 1.f);
  }
}

__global__ void dinv_k(const float* __restrict__ deg, float* __restrict__ dinv, int n) {
  int i = blockIdx.x * 256 + threadIdx.x;
  if (i < n) dinv[i] = rsqrtf(deg[i] + 1.f);   // +1 self-loop
}

// exclusive prefix sum of (int)deg -> rowptr[0..n]
__global__ void scan_k(const float* __restrict__ deg, int* __restrict__ rowptr, int n) {
  __shared__ int sh[1024];
  __shared__ int carry;
  const int tid = threadIdx.x;
  if (tid == 0) carry = 0;
  __syncthreads();
  for (int base = 0; base < n; base += 1024) {
    int i = base + tid;
    int v = (i < n) ? (int)deg[i] : 0;
    sh[tid] = v;
    __syncthreads();
    for (int off = 1; off < 1024; off <<= 1) {
      int t = (tid >= off) ? sh[tid - off] : 0;
      __syncthreads();
      sh[tid] += t;
      __syncthreads();
    }
    if (i < n) rowptr[i] = carry + sh[tid] - v;
    int tot = sh[1023];
    __syncthreads();
    if (tid == 0) carry += tot;
    __syncthreads();
  }
  if (tid == 0) rowptr[n] = carry;
}

__global__ void fill_k(const int* __restrict__ src, const int* __restrict__ dst,
                       const int* __restrict__ rowptr, int* __restrict__ cursor,
                       const float* __restrict__ dinv,
                       int* __restrict__ cidx, float* __restrict__ enrm, int ne, int n) {
  int i = blockIdx.x * 256 + threadIdx.x;
  if (i < ne) {
    int s = min(max(src[i], 0), n - 1);
    int d = min(max(dst[i], 0), n - 1);
    int p = atomicAdd(cursor + d, 1);
    int o = rowptr[d] + p;
    cidx[o] = s;
    enrm[o] = dinv[s] * dinv[d];
  }
}

// fused: out = relu( dinv[d]^2*y[d] + sum_e enrm*y[src] + b ), one wave per node
__global__ __launch_bounds__(256, 4) void gcn_gather(
    const float* __restrict__ y, const int* __restrict__ rowptr,
    const int* __restrict__ cidx, const float* __restrict__ enrm,
    const float* __restrict__ dinv, const float* __restrict__ b,
    float* __restrict__ out, int n)
{
  const int l = threadIdx.x & 63;
  const int wq = threadIdx.x >> 6;
  const int node = blockIdx.x * 4 + wq;
  if (node >= n) return;
  float dv = dinv[node];
  float2 acc = *(const float2*)(y + (size_t)node * 128 + l * 2);
  acc.x *= dv * dv; acc.y *= dv * dv;
  int r0 = rowptr[node], r1 = rowptr[node + 1];
  int e = r0;
  for (; e + 1 < r1; e += 2) {
    int s0 = cidx[e], s1 = cidx[e + 1];
    float n0 = enrm[e], n1 = enrm[e + 1];
    float2 v0 = *(const float2*)(y + (size_t)s0 * 128 + l * 2);
    float2 v1 = *(const float2*)(y + (size_t)s1 * 128 + l * 2);
    acc.x = fmaf(n0, v0.x, acc.x); acc.y = fmaf(n0, v0.y, acc.y);
    acc.x = fmaf(n1, v1.x, acc.x); acc.y = fmaf(n1, v1.y, acc.y);
  }
  if (e < r1) {
    int s0 = cidx[e];
    float n0 = enrm[e];
    float2 v0 = *(const float2*)(y + (size_t)s0 * 128 + l * 2);
    acc.x = fmaf(n0, v0.x, acc.x); acc.y = fmaf(n0, v0.y, acc.y);
  }
  float2 bb = *(const float2*)(b + l * 2);
  float2 o;
  o.x = fmaxf(acc.x + bb.x, 0.f);
  o.y = fmaxf(acc.y + bb.y, 0.f);
  *(float2*)(out + (size_t)node * 128 + l * 2) = o;
}

// ---------------------------------------------------------------- heads
__global__ __launch_bounds__(256, 2) void node_heads(
    const float* __restrict__ x,
    const float* __restrict__ cW1T, const float* __restrict__ cb1,
    const float* __restrict__ cW2T, const float* __restrict__ cb2,
    const float* __restrict__ uW1T, const float* __restrict__ ub1,
    const float* __restrict__ uW2,  const float* __restrict__ ub2,
    float* __restrict__ cls, float* __restrict__ unc, int n)
{
  int node = blockIdx.x * 256 + threadIdx.x;
  int nld = min(node, n - 1);
  const float* xp = x + (size_t)nld * 128;
  float hc[64], hu[64];
#pragma unroll
  for (int j = 0; j < 64; ++j) { hc[j] = cb1[j]; hu[j] = ub1[j]; }
  for (int k0 = 0; k0 < 128; k0 += 8) {
    float xk[8];
    *(float4*)&xk[0] = *(const float4*)(xp + k0);
    *(float4*)&xk[4] = *(const float4*)(xp + k0 + 4);
#pragma unroll
    for (int j = 0; j < 64; ++j) {
      const float* cw = cW1T + (size_t)j * 128 + k0;
      const float* uw = uW1T + (size_t)j * 128 + k0;
#pragma unroll
      for (int i = 0; i < 8; ++i) {
        hc[j] = fmaf(xk[i], cw[i], hc[j]);
        hu[j] = fmaf(xk[i], uw[i], hu[j]);
      }
    }
  }
  float vc0 = cb2[0], vc1 = cb2[1], vc2 = cb2[2], vc3 = cb2[3];
  float ua = ub2[0];
#pragma unroll
  for (int j = 0; j < 64; ++j) {
    float hcr = fmaxf(hc[j], 0.f), hur = fmaxf(hu[j], 0.f);
    vc0 = fmaf(hcr, cW2T[0 * 64 + j], vc0);
    vc1 = fmaf(hcr, cW2T[1 * 64 + j], vc1);
    vc2 = fmaf(hcr, cW2T[2 * 64 + j], vc2);
    vc3 = fmaf(hcr, cW2T[3 * 64 + j], vc3);
    ua  = fmaf(hur, uW2[j], ua);
  }
  if (node < n) {
    float4 vo; vo.x = vc0; vo.y = vc1; vo.z = vc2; vo.w = vc3;
    *(float4*)(cls + (size_t)node * 4) = vo;
    unc[node] = softplus_(ua);
  }
}

__global__ __launch_bounds__(256, 2) void edge_head(
    const float* __restrict__ P, const float* __restrict__ Q,
    const int* __restrict__ src, const int* __restrict__ dst,
    const float* __restrict__ b1,
    const float* __restrict__ eW2T, const float* __restrict__ b2,
    const float* __restrict__ eW3, const float* __restrict__ b3,
    float* __restrict__ ep, int ne, int n)
{
  __shared__ float H1[128][66];
  __shared__ float H2[64][64];
  const int lane = threadIdx.x & 63;
  const int wq = __builtin_amdgcn_readfirstlane(threadIdx.x >> 6);
  const int e0 = blockIdx.x * 64;
  {
    int el = threadIdx.x >> 2, q = threadIdx.x & 3;
    int e = min(e0 + el, ne - 1);
    int s = min(max(src[e], 0), n - 1);
    int d = min(max(dst[e], 0), n - 1);
    const float* pr = P + (size_t)s * 128 + q * 32;
    const float* qr = Q + (size_t)d * 128 + q * 32;
#pragma unroll
    for (int i = 0; i < 32; i += 4) {
      float4 a = *(const float4*)(pr + i);
      float4 c = *(const float4*)(qr + i);
      int jb = q * 32 + i;
      H1[jb + 0][el] = fmaxf(a.x + c.x + b1[jb + 0], 0.f);
      H1[jb + 1][el] = fmaxf(a.y + c.y + b1[jb + 1], 0.f);
      H1[jb + 2][el] = fmaxf(a.z + c.z + b1[jb + 2], 0.f);
      H1[jb + 3][el] = fmaxf(a.w + c.w + b1[jb + 3], 0.f);
    }
  }
  __syncthreads();
  float acc[16];
#pragma unroll
  for (int u = 0; u < 16; ++u) acc[u] = 0.f;
  gemm_tile<16, 66>(acc, &H1[0][0], 128, eW2T, 128, lane, wq);
#pragma unroll
  for (int u = 0; u < 16; ++u) {
    int col = wq * 16 + u;
    H2[col][lane] = fmaxf(acc[u] + b2[col], 0.f);
  }
  __syncthreads();
  if (wq == 0) {
    float a3 = b3[0];
    for (int k = 0; k < 64; ++k) a3 = fmaf(H2[k][lane], eW3[k], a3);
    int e = e0 + lane;
    if (e < ne) ep[e] = 1.f / (1.f + __expf(-a3));
  }
}

// ---------------------------------------------------------------- host
extern "C" void kernel_launch(void* const* d_in, const int* in_sizes, int n_in,
                              void* d_out, int out_size, void* d_ws, size_t ws_size,
                              hipStream_t stream)
{
  const float* seq   = (const float*)d_in[0];
  const int*   eidx  = (const int*)d_in[1];
  const float* Wih0  = (const float*)d_in[2];
  const float* Whh0  = (const float*)d_in[3];
  const float* bih0  = (const float*)d_in[4];
  const float* bhh0  = (const float*)d_in[5];
  const float* Wih1  = (const float*)d_in[6];
  const float* Whh1  = (const float*)d_in[7];
  const float* bih1  = (const float*)d_in[8];
  const float* bhh1  = (const float*)d_in[9];
  const float* encW1 = (const float*)d_in[10];
  const float* encb1 = (const float*)d_in[11];
  const float* encW2 = (const float*)d_in[12];
  const float* encb2 = (const float*)d_in[13];
  const float* gW0   = (const float*)d_in[14];
  const float* gb0   = (const float*)d_in[15];
  const float* gW1   = (const float*)d_in[16];
  const float* gb1   = (const float*)d_in[17];
  const float* gW2   = (const float*)d_in[18];
  const float* gb2   = (const float*)d_in[19];
  const float* eW1   = (const float*)d_in[20];
  const float* eb1   = (const float*)d_in[21];
  const float* eW2   = (const float*)d_in[22];
  const float* eb2   = (const float*)d_in[23];
  const float* eW3   = (const float*)d_in[24];
  const float* eb3   = (const float*)d_in[25];
  const float* cW1   = (const float*)d_in[26];
  const float* cb1   = (const float*)d_in[27];
  const float* cW2   = (const float*)d_in[28];
  const float* cb2   = (const float*)d_in[29];
  const float* uW1   = (const float*)d_in[30];
  const float* ub1   = (const float*)d_in[31];
  const float* uW2   = (const float*)d_in[32];
  const float* ub2   = (const float*)d_in[33];

  const int n  = in_sizes[0] / 320;     // 50000
  const int ne = in_sizes[1] / 2;       // 800000
  const int* src = eidx;
  const int* dst = eidx + ne;

  char* ws = (char*)d_ws;
  size_t off = 0;
  auto alloc = [&](size_t elems) -> float* {
    float* p = (float*)(ws + off);
    off += ((elems * 4 + 255) & ~(size_t)255);
    return p;
  };
  const size_t nb = (size_t)n * 128;
  float* B1     = alloc(nb);        // hf, later P
  float* B2     = alloc(nb);        // y / Q
  float* B4     = alloc(nb);        // x (gcn activations)
  float* latent = alloc((size_t)n * 64);
  float* deg    = alloc(n);
  float* dinv   = alloc(n);
  int*   rowptr = (int*)alloc(n + 1);
  int*   cursor = (int*)alloc(n);
  int*   cidx   = (int*)alloc(ne);
  float* enrm   = alloc(ne);
  float* encW1T = alloc(128 * 128);
  float* encW2T = alloc(64 * 128);
  float* gW0T   = alloc(128 * 64);
  float* gW1T   = alloc(128 * 128);
  float* gW2T   = alloc(128 * 128);
  float* eW1tT  = alloc(128 * 128);
  float* eW1bT  = alloc(128 * 128);
  float* eW2T   = alloc(64 * 128);
  float* cW1T   = alloc(64 * 128);
  float* cW2T   = alloc(4 * 64);
  float* uW1T   = alloc(64 * 128);
  unsigned short* Wp0 = (unsigned short*)alloc(20 * 512 * 8 / 2);
  unsigned short* Wp1 = (unsigned short*)alloc(32 * 512 * 8 / 2);
  float* bsum0  = alloc(512);
  float* bsum1  = alloc(512);
  (void)ws_size; (void)n_in; (void)out_size;

  float* xout = (float*)d_out;                    // [n][128]
  float* ep   = xout + nb;                        // [ne]
  float* cls  = ep + ne;                          // [n][4]
  float* unc  = cls + (size_t)n * 4;              // [n]

  auto T = [&](const float* s, float* d, int R, int C) {
    transpose_k<<<dim3((R * C + 255) / 256), dim3(256), 0, stream>>>(s, d, R, C);
  };
  T(encW1, encW1T, 128, 128);
  T(encW2, encW2T, 128, 64);
  T(gW0,   gW0T,   64, 128);
  T(gW1,   gW1T,   128, 128);
  T(gW2,   gW2T,   128, 128);
  T(eW1,            eW1tT, 128, 128);
  T(eW1 + 128*128,  eW1bT, 128, 128);
  T(eW2,   eW2T,   128, 64);
  T(cW1,   cW1T,   128, 64);
  T(cW2,   cW2T,   64, 4);
  T(uW1,   uW1T,   128, 64);

  prep_lstm_w<<<dim3((52 * 512 * 8 + 1024 + 255) / 256), dim3(256), 0, stream>>>(
      Wih0, Whh0, Wih1, Whh1, bih0, bhh0, bih1, bhh1, Wp0, Wp1, bsum0, bsum1);

  // ---- CSR build (once) ----
  hipMemsetAsync(deg, 0, (size_t)n * 4, stream);
  deg_count<<<dim3((ne + 255) / 256), dim3(256), 0, stream>>>(dst, deg, ne, n);
  dinv_k<<<dim3((n + 255) / 256), dim3(256), 0, stream>>>(deg, dinv, n);
  scan_k<<<dim3(1), dim3(1024), 0, stream>>>(deg, rowptr, n);
  hipMemsetAsync(cursor, 0, (size_t)n * 4, stream);
  fill_k<<<dim3((ne + 255) / 256), dim3(256), 0, stream>>>(
      src, dst, rowptr, cursor, dinv, cidx, enrm, ne, n);

  const int nblk = (n + 63) / 64;
  const int ntiles = nblk;
  // LSTM -> B1 (persistent, reg-resident weights)
  lstm_reg<<<dim3(256), dim3(512), 0, stream>>>(seq, Wp0, Wp1, bsum0, bsum1, B1, n, ntiles);

  // encoder: B1 -> B2 -> latent
  ngemm<128, 128, true,  true ><<<dim3(nblk), dim3(256), 0, stream>>>(B1, encW1T, encb1, B2, n);
  ngemm<128, 64,  false, true ><<<dim3(nblk), dim3(256), 0, stream>>>(B2, encW2T, encb2, latent, n);

  const int gblk = (n + 3) / 4;
  // GCN layer 0: latent(64) -> y(B2) -> gather -> B4
  ngemm<64, 128, false, false><<<dim3(nblk), dim3(256), 0, stream>>>(latent, gW0T, nullptr, B2, n);
  gcn_gather<<<dim3(gblk), dim3(256), 0, stream>>>(B2, rowptr, cidx, enrm, dinv, gb0, B4, n);
  // GCN layer 1
  ngemm<128, 128, false, false><<<dim3(nblk), dim3(256), 0, stream>>>(B4, gW1T, nullptr, B2, n);
  gcn_gather<<<dim3(gblk), dim3(256), 0, stream>>>(B2, rowptr, cidx, enrm, dinv, gb1, B4, n);
  // GCN layer 2 -> xout
  ngemm<128, 128, false, false><<<dim3(nblk), dim3(256), 0, stream>>>(B4, gW2T, nullptr, B2, n);
  gcn_gather<<<dim3(gblk), dim3(256), 0, stream>>>(B2, rowptr, cidx, enrm, dinv, gb2, xout, n);

  // edge head precompute: P = x@W1_top, Q = x@W1_bot
  ngemm<128, 128, false, false><<<dim3(nblk), dim3(256), 0, stream>>>(xout, eW1tT, nullptr, B1, n);
  ngemm<128, 128, false, false><<<dim3(nblk), dim3(256), 0, stream>>>(xout, eW1bT, nullptr, B2, n);
  edge_head<<<dim3((ne + 63) / 64), dim3(256), 0, stream>>>(
      B1, B2, src, dst, eb1, eW2T, eb2, eW3, eb3, ep, ne, n);

  node_heads<<<dim3((n + 255) / 256), dim3(256), 0, stream>>>(
      xout, cW1T, cb1, cW2T, cb2, uW1T, ub1, uW2, ub2, cls, unc, n);
}

// Round 4
// 3520.698 us; speedup vs baseline: 5.7843x; 1.0452x over previous
//
#include <hip/hip_runtime.h>
#include <math.h>

typedef float f32x4 __attribute__((ext_vector_type(4)));
typedef short s16x8 __attribute__((ext_vector_type(8)));

// ---------------------------------------------------------------- helpers
__device__ __forceinline__ float sigmoid_(float x) { return 1.f / (1.f + __expf(-x)); }
__device__ __forceinline__ float tanh_(float x) {
  x = fminf(fmaxf(x, -30.f), 30.f);
  float e = __expf(2.f * x);
  return (e - 1.f) / (e + 1.f);
}
__device__ __forceinline__ float softplus_(float x) {
  return (x > 15.f) ? x : log1pf(__expf(x));
}
__device__ __forceinline__ unsigned short f2bf(float f) {  // RNE fp32->bf16
  unsigned u = __float_as_uint(f);
  u += 0x7fffu + ((u >> 16) & 1u);
  return (unsigned short)(u >> 16);
}

// Per-thread GEMM tile: node = lane (64 nodes/block), wave wq owns CPT columns.
template<int CPT, int LDA>
__device__ __forceinline__ void gemm_tile(float* acc, const float* A, int K,
                                          const float* WT, int ldw, int lane, int wq)
{
  for (int k0 = 0; k0 < K; k0 += 8) {
    float a[8];
#pragma unroll
    for (int i = 0; i < 8; ++i) a[i] = A[(k0 + i) * LDA + lane];
#pragma unroll
    for (int u = 0; u < CPT; ++u) {
      const float* wr = WT + (size_t)(wq * CPT + u) * ldw + k0;
#pragma unroll
      for (int i = 0; i < 8; ++i) acc[u] = fmaf(a[i], wr[i], acc[u]);
    }
  }
}

// ---------------------------------------------------------------- LSTM weight prep
// Wp0: [20 chunks][512 cols][8] bf16 ; k<16 -> Wih0, 16..31 -> 0 (pad), 32..159 -> Whh0
// Wp1: [32 chunks][512 cols][8] bf16 ; k<128 -> Wih1, else Whh1
__global__ void prep_lstm_w(const float* __restrict__ Wih0, const float* __restrict__ Whh0,
                            const float* __restrict__ Wih1, const float* __restrict__ Whh1,
                            const float* __restrict__ bih0, const float* __restrict__ bhh0,
                            const float* __restrict__ bih1, const float* __restrict__ bhh1,
                            unsigned short* __restrict__ Wp0, unsigned short* __restrict__ Wp1,
                            float* __restrict__ bs0, float* __restrict__ bs1)
{
  int idx = blockIdx.x * 256 + threadIdx.x;
  if (idx < 20 * 512 * 8) {
    int c = idx >> 12, rem = idx & 4095;
    int col = rem >> 3, e = rem & 7;
    int k = c * 8 + e;
    float v = 0.f;
    if (k < 16) v = Wih0[col * 16 + k];
    else if (k >= 32) v = Whh0[col * 128 + (k - 32)];
    Wp0[idx] = f2bf(v);
  }
  int i1 = idx - 20 * 512 * 8;
  if (i1 >= 0 && i1 < 32 * 512 * 8) {
    int c = i1 >> 12, rem = i1 & 4095;
    int col = rem >> 3, e = rem & 7;
    int k = c * 8 + e;
    float v = (k < 128) ? Wih1[col * 128 + k] : Whh1[col * 128 + (k - 128)];
    Wp1[i1] = f2bf(v);
  }
  int i2 = idx - 52 * 512 * 8;
  if (i2 >= 0 && i2 < 512) bs0[i2] = bih0[i2] + bhh0[i2];
  int i3 = i2 - 512;
  if (i3 >= 0 && i3 < 512) bs1[i3] = bih1[i3] + bhh1[i3];
}

// ---------------------------------------------------------------- LSTM epilogue (shared)
__device__ __forceinline__ void lstm_epi_m(const f32x4 (&acc)[4][4], f32x4 (&cs)[4],
    const float (&bs)[4], unsigned short* __restrict__ lds, int uoff, int kq,
    int nodebase, float* __restrict__ hf, int u, int n, bool last)
{
#pragma unroll
  for (int m = 0; m < 4; ++m) {
#pragma unroll
    for (int r = 0; r < 4; ++r) {
      float gi = acc[m][0][r] + bs[0];
      float gf = acc[m][1][r] + bs[1];
      float gg = acc[m][2][r] + bs[2];
      float go = acc[m][3][r] + bs[3];
      float c = sigmoid_(gf) * cs[m][r] + sigmoid_(gi) * tanh_(gg);
      cs[m][r] = c;
      float h = sigmoid_(go) * tanh_(c);
      int node = m * 16 + kq * 4 + r;
      lds[uoff + node * 8] = f2bf(h);
      if (last) {
        int gn = nodebase + node;
        if (gn < n) hf[(size_t)gn * 128 + u] = h;
      }
    }
  }
}

// ---------------------------------------------------------------- LSTM layer 0 (weights reg-resident)
// h0seq layout per slab-tile tt, step t: [16 chunks][64 nodes][8] bf16 = 16 KB
__global__ __launch_bounds__(512, 2) void lstm_l0(
    const float* __restrict__ seq, const unsigned short* __restrict__ Wp0,
    const float* __restrict__ bs0, unsigned short* __restrict__ h0seq,
    int n, int tile0, int ntiles)
{
  __shared__ __align__(16) unsigned short A0[20 * 512];
  const int tid = threadIdx.x;
  const int l = tid & 63;
  const int wq = __builtin_amdgcn_readfirstlane(tid >> 6);
  const int kq = l >> 4;
  const int la = (l & 15) * 8;
  const int colu = wq * 16 + (l & 15);
  const int uoff = (4 + (colu >> 3)) * 512 + (colu & 7);

  s16x8 b0[5][4];
#pragma unroll
  for (int kc = 0; kc < 5; ++kc)
#pragma unroll
    for (int g = 0; g < 4; ++g)
      b0[kc][g] = *(const s16x8*)&Wp0[(size_t)(kc * 4 + kq) * 4096 + (g * 128 + colu) * 8];
  float bsr[4];
#pragma unroll
  for (int g = 0; g < 4; ++g) bsr[g] = bs0[g * 128 + colu];
  const f32x4 zero4 = {0.f, 0.f, 0.f, 0.f};

  for (int tt = blockIdx.x; tt < ntiles; tt += gridDim.x) {
    const int nodebase = (tile0 + tt) * 64;
    const int nld = min(nodebase + (tid >> 2), n - 1);
    unsigned short* __restrict__ hdst = h0seq + (size_t)tt * 20 * 8192;
    for (int i = tid; i < 18 * 512; i += 512) A0[2 * 512 + i] = 0;
    if (tid < 256) {
      int nd = tid >> 2, q = tid & 3;
      float4 v = *(const float4*)(seq + (size_t)nld * 320 + q * 4);
      unsigned d0 = (unsigned)f2bf(v.x) | ((unsigned)f2bf(v.y) << 16);
      unsigned d1 = (unsigned)f2bf(v.z) | ((unsigned)f2bf(v.w) << 16);
      unsigned* dstp = (unsigned*)&A0[(q >> 1) * 512 + nd * 8 + (q & 1) * 4];
      dstp[0] = d0; dstp[1] = d1;
    }
    f32x4 c0[4];
#pragma unroll
    for (int m = 0; m < 4; ++m) c0[m] = zero4;
    __syncthreads();

    for (int t = 0; t < 20; ++t) {
      float4 xnext;
      const bool ldx = (t < 19) && (tid < 256);
      if (ldx) xnext = *(const float4*)(seq + (size_t)nld * 320 + (t + 1) * 16 + (tid & 3) * 4);

      f32x4 acc[4][4];
#pragma unroll
      for (int m = 0; m < 4; ++m)
#pragma unroll
        for (int g = 0; g < 4; ++g) acc[m][g] = zero4;
#pragma unroll
      for (int kc = 0; kc < 5; ++kc) {
        s16x8 av[4];
#pragma unroll
        for (int m = 0; m < 4; ++m)
          av[m] = *(const s16x8*)&A0[(kc * 4 + kq) * 512 + m * 128 + la];
#pragma unroll
        for (int g = 0; g < 4; ++g)
#pragma unroll
          for (int m = 0; m < 4; ++m)
            acc[m][g] = __builtin_amdgcn_mfma_f32_16x16x32_bf16(av[m], b0[kc][g], acc[m][g], 0, 0, 0);
      }
      __syncthreads();                 // MFMA reads of A0 done
      lstm_epi_m(acc, c0, bsr, A0, uoff, kq, 0, nullptr, colu, 0, false);
      if (ldx) {
        int nd = tid >> 2, q = tid & 3;
        unsigned d0 = (unsigned)f2bf(xnext.x) | ((unsigned)f2bf(xnext.y) << 16);
        unsigned d1 = (unsigned)f2bf(xnext.z) | ((unsigned)f2bf(xnext.w) << 16);
        unsigned* dstp = (unsigned*)&A0[(q >> 1) * 512 + nd * 8 + (q & 1) * 4];
        dstp[0] = d0; dstp[1] = d1;
      }
      __syncthreads();                 // h0(t) + x(t+1) visible
      // coalesced LDS->global copy of h0(t) (reads overlap next iteration's MFMA)
      {
        s16x8 u0 = *(const s16x8*)&A0[2048 + tid * 8];
        s16x8 u1 = *(const s16x8*)&A0[2048 + 4096 + tid * 8];
        *(s16x8*)&hdst[(size_t)t * 8192 + tid * 8] = u0;
        *(s16x8*)&hdst[(size_t)t * 8192 + 4096 + tid * 8] = u1;
      }
    }
  }
}

// ---------------------------------------------------------------- LSTM layer 1 (weights reg-resident)
__global__ __launch_bounds__(512, 2) void lstm_l1(
    const unsigned short* __restrict__ h0seq, const unsigned short* __restrict__ Wp1,
    const float* __restrict__ bs1, float* __restrict__ hfinal,
    int n, int tile0, int ntiles)
{
  __shared__ __align__(16) unsigned short A1[48 * 512];  // 0..15 h0 buf0, 16..31 h0 buf1, 32..47 h1
  const int tid = threadIdx.x;
  const int l = tid & 63;
  const int wq = __builtin_amdgcn_readfirstlane(tid >> 6);
  const int kq = l >> 4;
  const int la = (l & 15) * 8;
  const int colu = wq * 16 + (l & 15);
  const int uoff = (32 + (colu >> 3)) * 512 + (colu & 7);

  s16x8 b1[8][4];
#pragma unroll
  for (int kc = 0; kc < 8; ++kc)
#pragma unroll
    for (int g = 0; g < 4; ++g)
      b1[kc][g] = *(const s16x8*)&Wp1[(size_t)(kc * 4 + kq) * 4096 + (g * 128 + colu) * 8];
  float bsr[4];
#pragma unroll
  for (int g = 0; g < 4; ++g) bsr[g] = bs1[g * 128 + colu];
  const f32x4 zero4 = {0.f, 0.f, 0.f, 0.f};

  for (int tt = blockIdx.x; tt < ntiles; tt += gridDim.x) {
    const int nodebase = (tile0 + tt) * 64;
    const unsigned short* __restrict__ hsrc = h0seq + (size_t)tt * 20 * 8192;
    for (int i = tid; i < 16 * 512; i += 512) A1[32 * 512 + i] = 0;
    {  // stage h0(0) -> buf0
      s16x8 s0 = *(const s16x8*)&hsrc[tid * 8];
      s16x8 s1 = *(const s16x8*)&hsrc[4096 + tid * 8];
      *(s16x8*)&A1[tid * 8] = s0;
      *(s16x8*)&A1[4096 + tid * 8] = s1;
    }
    f32x4 c1[4];
#pragma unroll
    for (int m = 0; m < 4; ++m) c1[m] = zero4;
    __syncthreads();

    for (int t = 0; t < 20; ++t) {
      s16x8 p0, p1;
      const bool ld = (t < 19);
      if (ld) {
        p0 = *(const s16x8*)&hsrc[(size_t)(t + 1) * 8192 + tid * 8];
        p1 = *(const s16x8*)&hsrc[(size_t)(t + 1) * 8192 + 4096 + tid * 8];
      }
      const int hb = (t & 1) * 16;
      f32x4 acc[4][4];
#pragma unroll
      for (int m = 0; m < 4; ++m)
#pragma unroll
        for (int g = 0; g < 4; ++g) acc[m][g] = zero4;
#pragma unroll
      for (int kc = 0; kc < 8; ++kc) {
        const int ch = (kc < 4) ? (hb + kc * 4 + kq) : (32 + (kc - 4) * 4 + kq);
        s16x8 av[4];
#pragma unroll
        for (int m = 0; m < 4; ++m)
          av[m] = *(const s16x8*)&A1[ch * 512 + m * 128 + la];
#pragma unroll
        for (int g = 0; g < 4; ++g)
#pragma unroll
          for (int m = 0; m < 4; ++m)
            acc[m][g] = __builtin_amdgcn_mfma_f32_16x16x32_bf16(av[m], b1[kc][g], acc[m][g], 0, 0, 0);
      }
      __syncthreads();                 // MFMA reads done
      lstm_epi_m(acc, c1, bsr, A1, uoff, kq, nodebase, hfinal, colu, n, t == 19);
      if (ld) {                        // write prefetched h0(t+1) to other buf
        const int ob = ((t + 1) & 1) * 16 * 512;
        *(s16x8*)&A1[ob + tid * 8] = p0;
        *(s16x8*)&A1[ob + 4096 + tid * 8] = p1;
      }
      __syncthreads();                 // h1(t) + h0(t+1) visible
    }
  }
}

// ---------------------------------------------------------------- LSTM fused fallback (small ws)
__global__ __launch_bounds__(512, 1) void lstm_reg(
    const float* __restrict__ seq,
    const unsigned short* __restrict__ Wp0, const unsigned short* __restrict__ Wp1,
    const float* __restrict__ bs0, const float* __restrict__ bs1,
    float* __restrict__ hfinal, int n, int ntiles)
{
  __shared__ __align__(16) unsigned short Abuf[36 * 512];
  const int tid = threadIdx.x;
  const int l = tid & 63;
  const int wq = __builtin_amdgcn_readfirstlane(tid >> 6);
  const int kq = l >> 4;
  const int la = (l & 15) * 8;
  const int colu = wq * 16 + (l & 15);
  const int uoff0 = (4 + (colu >> 3)) * 512 + (colu & 7);
  const int uoff1 = (20 + (colu >> 3)) * 512 + (colu & 7);

  float bsr0[4], bsr1[4];
#pragma unroll
  for (int g = 0; g < 4; ++g) {
    bsr0[g] = bs0[g * 128 + colu];
    bsr1[g] = bs1[g * 128 + colu];
  }
  const f32x4 zero4 = {0.f, 0.f, 0.f, 0.f};

  for (int tile = blockIdx.x; tile < ntiles; tile += gridDim.x) {
    const int nodebase = tile * 64;
    const int nld = min(nodebase + (tid >> 2), n - 1);
    for (int i = tid; i < 34 * 512; i += 512) Abuf[2 * 512 + i] = 0;
    if (tid < 256) {
      int nd = tid >> 2, q = tid & 3;
      float4 v = *(const float4*)(seq + (size_t)nld * 320 + q * 4);
      unsigned d0 = (unsigned)f2bf(v.x) | ((unsigned)f2bf(v.y) << 16);
      unsigned d1 = (unsigned)f2bf(v.z) | ((unsigned)f2bf(v.w) << 16);
      unsigned* dst = (unsigned*)&Abuf[(q >> 1) * 512 + nd * 8 + (q & 1) * 4];
      dst[0] = d0; dst[1] = d1;
    }
    f32x4 c0[4], c1[4];
#pragma unroll
    for (int m = 0; m < 4; ++m) { c0[m] = zero4; c1[m] = zero4; }
    __syncthreads();

    for (int t = 0; t < 20; ++t) {
      float4 xnext;
      const bool ldx = (t < 19) && (tid < 256);
      if (ldx) xnext = *(const float4*)(seq + (size_t)nld * 320 + (t + 1) * 16 + (tid & 3) * 4);

      f32x4 acc[4][4];
#pragma unroll
      for (int m = 0; m < 4; ++m)
#pragma unroll
        for (int g = 0; g < 4; ++g) acc[m][g] = zero4;
#pragma unroll
      for (int kc = 0; kc < 5; ++kc) {
        s16x8 av[4];
#pragma unroll
        for (int m = 0; m < 4; ++m)
          av[m] = *(const s16x8*)&Abuf[(kc * 4 + kq) * 512 + m * 128 + la];
#pragma unroll
        for (int g = 0; g < 4; ++g) {
          s16x8 bv = *(const s16x8*)&Wp0[(size_t)(kc * 4 + kq) * 4096 + (g * 128 + colu) * 8];
#pragma unroll
          for (int m = 0; m < 4; ++m)
            acc[m][g] = __builtin_amdgcn_mfma_f32_16x16x32_bf16(av[m], bv, acc[m][g], 0, 0, 0);
        }
      }
      __syncthreads();
      lstm_epi_m(acc, c0, bsr0, Abuf, uoff0, kq, nodebase, hfinal, colu, n, false);
      if (ldx) {
        int nd = tid >> 2, q = tid & 3;
        unsigned d0 = (unsigned)f2bf(xnext.x) | ((unsigned)f2bf(xnext.y) << 16);
        unsigned d1 = (unsigned)f2bf(xnext.z) | ((unsigned)f2bf(xnext.w) << 16);
        unsigned* dst = (unsigned*)&Abuf[(q >> 1) * 512 + nd * 8 + (q & 1) * 4];
        dst[0] = d0; dst[1] = d1;
      }
      __syncthreads();

#pragma unroll
      for (int m = 0; m < 4; ++m)
#pragma unroll
        for (int g = 0; g < 4; ++g) acc[m][g] = zero4;
#pragma unroll
      for (int kc = 0; kc < 8; ++kc) {
        s16x8 av[4];
#pragma unroll
        for (int m = 0; m < 4; ++m)
          av[m] = *(const s16x8*)&Abuf[(4 + kc * 4 + kq) * 512 + m * 128 + la];
#pragma unroll
        for (int g = 0; g < 4; ++g) {
          s16x8 bv = *(const s16x8*)&Wp1[(size_t)(kc * 4 + kq) * 4096 + (g * 128 + colu) * 8];
#pragma unroll
          for (int m = 0; m < 4; ++m)
            acc[m][g] = __builtin_amdgcn_mfma_f32_16x16x32_bf16(av[m], bv, acc[m][g], 0, 0, 0);
        }
      }
      __syncthreads();
      lstm_epi_m(acc, c1, bsr1, Abuf, uoff1, kq, nodebase, hfinal, colu, n, t == 19);
      __syncthreads();
    }
  }
}

// ---------------------------------------------------------------- generic node GEMM
template<int KDIM, int COLS, bool RELU, bool BIAS>
__global__ __launch_bounds__(256, 4) void ngemm(
    const float* __restrict__ xin, const float* __restrict__ WT,
    const float* __restrict__ b, float* __restrict__ out, int n)
{
  __shared__ float A[KDIM][65];
  const int lane = threadIdx.x & 63;
  const int wq = __builtin_amdgcn_readfirstlane(threadIdx.x >> 6);
  const int node = blockIdx.x * 64 + lane;

  for (int i = threadIdx.x; i < 64 * KDIM; i += 256) {
    int nn = i / KDIM, k = i % KDIM;
    int g = min(blockIdx.x * 64 + nn, n - 1);
    A[k][nn] = xin[(size_t)g * KDIM + k];
  }
  __syncthreads();

  constexpr int CPT = COLS / 4;
  float acc[CPT];
#pragma unroll
  for (int u = 0; u < CPT; ++u) acc[u] = 0.f;
  gemm_tile<CPT, 65>(acc, &A[0][0], KDIM, WT, KDIM, lane, wq);

  if (node < n) {
#pragma unroll
    for (int u = 0; u < CPT; ++u) {
      int col = wq * CPT + u;
      float v = acc[u];
      if (BIAS) v += b[col];
      if (RELU) v = fmaxf(v, 0.f);
      out[(size_t)node * COLS + col] = v;
    }
  }
}

// ---------------------------------------------------------------- small utility kernels
__global__ void transpose_k(const float* __restrict__ s, float* __restrict__ d, int R, int C) {
  int i = blockIdx.x * 256 + threadIdx.x;
  if (i < R * C) { int r = i / C, c = i % C; d[(size_t)c * R + r] = s[i]; }
}

__global__ void deg_count(const int* __restrict__ dst, float* __restrict__ deg, int ne, int n) {
  int i = blockIdx.x * 256 + threadIdx.x;
  if (i < ne) {
    int d = dst[i]; d = min(max(d, 0), n - 1);
    atomicAdd(deg + d, 1.f);
  }
}

__global__ void dinv_k(const float* __restrict__ deg, float* __restrict__ dinv, int n) {
  int i = blockIdx.x * 256 + threadIdx.x;
  if (i < n) dinv[i] = rsqrtf(deg[i] + 1.f);   // +1 self-loop
}

// exclusive prefix sum of (int)deg -> rowptr[0..n]
__global__ void scan_k(const float* __restrict__ deg, int* __restrict__ rowptr, int n) {
  __shared__ int sh[1024];
  __shared__ int carry;
  const int tid = threadIdx.x;
  if (tid == 0) carry = 0;
  __syncthreads();
  for (int base = 0; base < n; base += 1024) {
    int i = base + tid;
    int v = (i < n) ? (int)deg[i] : 0;
    sh[tid] = v;
    __syncthreads();
    for (int off = 1; off < 1024; off <<= 1) {
      int t = (tid >= off) ? sh[tid - off] : 0;
      __syncthreads();
      sh[tid] += t;
      __syncthreads();
    }
    if (i < n) rowptr[i] = carry + sh[tid] - v;
    int tot = sh[1023];
    __syncthreads();
    if (tid == 0) carry += tot;
    __syncthreads();
  }
  if (tid == 0) rowptr[n] = carry;
}

__global__ void fill_k(const int* __restrict__ src, const int* __restrict__ dst,
                       const int* __restrict__ rowptr, int* __restrict__ cursor,
                       const float* __restrict__ dinv,
                       int* __restrict__ cidx, float* __restrict__ enrm, int ne, int n) {
  int i = blockIdx.x * 256 + threadIdx.x;
  if (i < ne) {
    int s = min(max(src[i], 0), n - 1);
    int d = min(max(dst[i], 0), n - 1);
    int p = atomicAdd(cursor + d, 1);
    int o = rowptr[d] + p;
    cidx[o] = s;
    enrm[o] = dinv[s] * dinv[d];
  }
}

// fused: out = relu( dinv[d]^2*y[d] + sum_e enrm*y[src] + b ), one wave per node
__global__ __launch_bounds__(256, 4) void gcn_gather(
    const float* __restrict__ y, const int* __restrict__ rowptr,
    const int* __restrict__ cidx, const float* __restrict__ enrm,
    const float* __restrict__ dinv, const float* __restrict__ b,
    float* __restrict__ out, int n)
{
  const int l = threadIdx.x & 63;
  const int wq = threadIdx.x >> 6;
  const int node = blockIdx.x * 4 + wq;
  if (node >= n) return;
  float dv = dinv[node];
  float2 acc = *(const float2*)(y + (size_t)node * 128 + l * 2);
  acc.x *= dv * dv; acc.y *= dv * dv;
  int r0 = rowptr[node], r1 = rowptr[node + 1];
  int e = r0;
  for (; e + 1 < r1; e += 2) {
    int s0 = cidx[e], s1 = cidx[e + 1];
    float n0 = enrm[e], n1 = enrm[e + 1];
    float2 v0 = *(const float2*)(y + (size_t)s0 * 128 + l * 2);
    float2 v1 = *(const float2*)(y + (size_t)s1 * 128 + l * 2);
    acc.x = fmaf(n0, v0.x, acc.x); acc.y = fmaf(n0, v0.y, acc.y);
    acc.x = fmaf(n1, v1.x, acc.x); acc.y = fmaf(n1, v1.y, acc.y);
  }
  if (e < r1) {
    int s0 = cidx[e];
    float n0 = enrm[e];
    float2 v0 = *(const float2*)(y + (size_t)s0 * 128 + l * 2);
    acc.x = fmaf(n0, v0.x, acc.x); acc.y = fmaf(n0, v0.y, acc.y);
  }
  float2 bb = *(const float2*)(b + l * 2);
  float2 o;
  o.x = fmaxf(acc.x + bb.x, 0.f);
  o.y = fmaxf(acc.y + bb.y, 0.f);
  *(float2*)(out + (size_t)node * 128 + l * 2) = o;
}

// ---------------------------------------------------------------- heads
__global__ __launch_bounds__(256, 2) void node_heads(
    const float* __restrict__ x,
    const float* __restrict__ cW1T, const float* __restrict__ cb1,
    const float* __restrict__ cW2T, const float* __restrict__ cb2,
    const float* __restrict__ uW1T, const float* __restrict__ ub1,
    const float* __restrict__ uW2,  const float* __restrict__ ub2,
    float* __restrict__ cls, float* __restrict__ unc, int n)
{
  int node = blockIdx.x * 256 + threadIdx.x;
  int nld = min(node, n - 1);
  const float* xp = x + (size_t)nld * 128;
  float hc[64], hu[64];
#pragma unroll
  for (int j = 0; j < 64; ++j) { hc[j] = cb1[j]; hu[j] = ub1[j]; }
  for (int k0 = 0; k0 < 128; k0 += 8) {
    float xk[8];
    *(float4*)&xk[0] = *(const float4*)(xp + k0);
    *(float4*)&xk[4] = *(const float4*)(xp + k0 + 4);
#pragma unroll
    for (int j = 0; j < 64; ++j) {
      const float* cw = cW1T + (size_t)j * 128 + k0;
      const float* uw = uW1T + (size_t)j * 128 + k0;
#pragma unroll
      for (int i = 0; i < 8; ++i) {
        hc[j] = fmaf(xk[i], cw[i], hc[j]);
        hu[j] = fmaf(xk[i], uw[i], hu[j]);
      }
    }
  }
  float vc0 = cb2[0], vc1 = cb2[1], vc2 = cb2[2], vc3 = cb2[3];
  float ua = ub2[0];
#pragma unroll
  for (int j = 0; j < 64; ++j) {
    float hcr = fmaxf(hc[j], 0.f), hur = fmaxf(hu[j], 0.f);
    vc0 = fmaf(hcr, cW2T[0 * 64 + j], vc0);
    vc1 = fmaf(hcr, cW2T[1 * 64 + j], vc1);
    vc2 = fmaf(hcr, cW2T[2 * 64 + j], vc2);
    vc3 = fmaf(hcr, cW2T[3 * 64 + j], vc3);
    ua  = fmaf(hur, uW2[j], ua);
  }
  if (node < n) {
    float4 vo; vo.x = vc0; vo.y = vc1; vo.z = vc2; vo.w = vc3;
    *(float4*)(cls + (size_t)node * 4) = vo;
    unc[node] = softplus_(ua);
  }
}

__global__ __launch_bounds__(256, 2) void edge_head(
    const float* __restrict__ P, const float* __restrict__ Q,
    const int* __restrict__ src, const int* __restrict__ dst,
    const float* __restrict__ b1,
    const float* __restrict__ eW2T, const float* __restrict__ b2,
    const float* __restrict__ eW3, const float* __restrict__ b3,
    float* __restrict__ ep, int ne, int n)
{
  __shared__ float H1[128][66];
  __shared__ float H2[64][64];
  const int lane = threadIdx.x & 63;
  const int wq = __builtin_amdgcn_readfirstlane(threadIdx.x >> 6);
  const int e0 = blockIdx.x * 64;
  {
    int el = threadIdx.x >> 2, q = threadIdx.x & 3;
    int e = min(e0 + el, ne - 1);
    int s = min(max(src[e], 0), n - 1);
    int d = min(max(dst[e], 0), n - 1);
    const float* pr = P + (size_t)s * 128 + q * 32;
    const float* qr = Q + (size_t)d * 128 + q * 32;
#pragma unroll
    for (int i = 0; i < 32; i += 4) {
      float4 a = *(const float4*)(pr + i);
      float4 c = *(const float4*)(qr + i);
      int jb = q * 32 + i;
      H1[jb + 0][el] = fmaxf(a.x + c.x + b1[jb + 0], 0.f);
      H1[jb + 1][el] = fmaxf(a.y + c.y + b1[jb + 1], 0.f);
      H1[jb + 2][el] = fmaxf(a.z + c.z + b1[jb + 2], 0.f);
      H1[jb + 3][el] = fmaxf(a.w + c.w + b1[jb + 3], 0.f);
    }
  }
  __syncthreads();
  float acc[16];
#pragma unroll
  for (int u = 0; u < 16; ++u) acc[u] = 0.f;
  gemm_tile<16, 66>(acc, &H1[0][0], 128, eW2T, 128, lane, wq);
#pragma unroll
  for (int u = 0; u < 16; ++u) {
    int col = wq * 16 + u;
    H2[col][lane] = fmaxf(acc[u] + b2[col], 0.f);
  }
  __syncthreads();
  if (wq == 0) {
    float a3 = b3[0];
    for (int k = 0; k < 64; ++k) a3 = fmaf(H2[k][lane], eW3[k], a3);
    int e = e0 + lane;
    if (e < ne) ep[e] = 1.f / (1.f + __expf(-a3));
  }
}

// ---------------------------------------------------------------- host
extern "C" void kernel_launch(void* const* d_in, const int* in_sizes, int n_in,
                              void* d_out, int out_size, void* d_ws, size_t ws_size,
                              hipStream_t stream)
{
  const float* seq   = (const float*)d_in[0];
  const int*   eidx  = (const int*)d_in[1];
  const float* Wih0  = (const float*)d_in[2];
  const float* Whh0  = (const float*)d_in[3];
  const float* bih0  = (const float*)d_in[4];
  const float* bhh0  = (const float*)d_in[5];
  const float* Wih1  = (const float*)d_in[6];
  const float* Whh1  = (const float*)d_in[7];
  const float* bih1  = (const float*)d_in[8];
  const float* bhh1  = (const float*)d_in[9];
  const float* encW1 = (const float*)d_in[10];
  const float* encb1 = (const float*)d_in[11];
  const float* encW2 = (const float*)d_in[12];
  const float* encb2 = (const float*)d_in[13];
  const float* gW0   = (const float*)d_in[14];
  const float* gb0   = (const float*)d_in[15];
  const float* gW1   = (const float*)d_in[16];
  const float* gb1   = (const float*)d_in[17];
  const float* gW2   = (const float*)d_in[18];
  const float* gb2   = (const float*)d_in[19];
  const float* eW1   = (const float*)d_in[20];
  const float* eb1   = (const float*)d_in[21];
  const float* eW2   = (const float*)d_in[22];
  const float* eb2   = (const float*)d_in[23];
  const float* eW3   = (const float*)d_in[24];
  const float* eb3   = (const float*)d_in[25];
  const float* cW1   = (const float*)d_in[26];
  const float* cb1   = (const float*)d_in[27];
  const float* cW2   = (const float*)d_in[28];
  const float* cb2   = (const float*)d_in[29];
  const float* uW1   = (const float*)d_in[30];
  const float* ub1   = (const float*)d_in[31];
  const float* uW2   = (const float*)d_in[32];
  const float* ub2   = (const float*)d_in[33];

  const int n  = in_sizes[0] / 320;     // 50000
  const int ne = in_sizes[1] / 2;       // 800000
  const int* src = eidx;
  const int* dst = eidx + ne;

  char* ws = (char*)d_ws;
  size_t off = 0;
  auto alloc = [&](size_t elems) -> float* {
    float* p = (float*)(ws + off);
    off += ((elems * 4 + 255) & ~(size_t)255);
    return p;
  };
  const size_t nb = (size_t)n * 128;
  float* B1     = alloc(nb);        // hf, later P
  float* B2     = alloc(nb);        // y / Q
  float* B4     = alloc(nb);        // x (gcn activations)
  float* latent = alloc((size_t)n * 64);
  float* deg    = alloc(n);
  float* dinv   = alloc(n);
  int*   rowptr = (int*)alloc(n + 1);
  int*   cursor = (int*)alloc(n);
  int*   cidx   = (int*)alloc(ne);
  float* enrm   = alloc(ne);
  float* encW1T = alloc(128 * 128);
  float* encW2T = alloc(64 * 128);
  float* gW0T   = alloc(128 * 64);
  float* gW1T   = alloc(128 * 128);
  float* gW2T   = alloc(128 * 128);
  float* eW1tT  = alloc(128 * 128);
  float* eW1bT  = alloc(128 * 128);
  float* eW2T   = alloc(64 * 128);
  float* cW1T   = alloc(64 * 128);
  float* cW2T   = alloc(4 * 64);
  float* uW1T   = alloc(64 * 128);
  unsigned short* Wp0 = (unsigned short*)alloc(20 * 512 * 8 / 2);
  unsigned short* Wp1 = (unsigned short*)alloc(32 * 512 * 8 / 2);
  float* bsum0  = alloc(512);
  float* bsum1  = alloc(512);
  (void)n_in; (void)out_size;

  float* xout = (float*)d_out;                    // [n][128]
  float* ep   = xout + nb;                        // [ne]
  float* cls  = ep + ne;                          // [n][4]
  float* unc  = cls + (size_t)n * 4;              // [n]

  auto T = [&](const float* s, float* d, int R, int C) {
    transpose_k<<<dim3((R * C + 255) / 256), dim3(256), 0, stream>>>(s, d, R, C);
  };
  T(encW1, encW1T, 128, 128);
  T(encW2, encW2T, 128, 64);
  T(gW0,   gW0T,   64, 128);
  T(gW1,   gW1T,   128, 128);
  T(gW2,   gW2T,   128, 128);
  T(eW1,            eW1tT, 128, 128);
  T(eW1 + 128*128,  eW1bT, 128, 128);
  T(eW2,   eW2T,   128, 64);
  T(cW1,   cW1T,   128, 64);
  T(cW2,   cW2T,   64, 4);
  T(uW1,   uW1T,   128, 64);

  prep_lstm_w<<<dim3((52 * 512 * 8 + 1024 + 255) / 256), dim3(256), 0, stream>>>(
      Wih0, Whh0, Wih1, Whh1, bih0, bhh0, bih1, bhh1, Wp0, Wp1, bsum0, bsum1);

  // ---- CSR build (once) ----
  hipMemsetAsync(deg, 0, (size_t)n * 4, stream);
  deg_count<<<dim3((ne + 255) / 256), dim3(256), 0, stream>>>(dst, deg, ne, n);
  dinv_k<<<dim3((n + 255) / 256), dim3(256), 0, stream>>>(deg, dinv, n);
  scan_k<<<dim3(1), dim3(1024), 0, stream>>>(deg, rowptr, n);
  hipMemsetAsync(cursor, 0, (size_t)n * 4, stream);
  fill_k<<<dim3((ne + 255) / 256), dim3(256), 0, stream>>>(
      src, dst, rowptr, cursor, dinv, cidx, enrm, ne, n);

  const int nblk = (n + 63) / 64;
  const int ntiles = nblk;

  // ---- LSTM: layer-split with reg-resident weights; h0 sequence staged in ws ----
  const size_t per_tile = (size_t)20 * 8192 * sizeof(unsigned short);   // 320 KB
  size_t avail = (ws_size > off) ? (ws_size - off) : 0;
  int slab_tiles = (int)((avail / per_tile < (size_t)ntiles) ? (avail / per_tile) : (size_t)ntiles);
  if (slab_tiles >= 8) {
    unsigned short* h0seq = (unsigned short*)(ws + off);
    for (int t0 = 0; t0 < ntiles; t0 += slab_tiles) {
      int st = (ntiles - t0 < slab_tiles) ? (ntiles - t0) : slab_tiles;
      int grid = (st < 256) ? st : 256;
      lstm_l0<<<dim3(grid), dim3(512), 0, stream>>>(seq, Wp0, bsum0, h0seq, n, t0, st);
      lstm_l1<<<dim3(grid), dim3(512), 0, stream>>>(h0seq, Wp1, bsum1, B1, n, t0, st);
    }
  } else {
    lstm_reg<<<dim3(256), dim3(512), 0, stream>>>(seq, Wp0, Wp1, bsum0, bsum1, B1, n, ntiles);
  }

  // encoder: B1 -> B2 -> latent
  ngemm<128, 128, true,  true ><<<dim3(nblk), dim3(256), 0, stream>>>(B1, encW1T, encb1, B2, n);
  ngemm<128, 64,  false, true ><<<dim3(nblk), dim3(256), 0, stream>>>(B2, encW2T, encb2, latent, n);

  const int gblk = (n + 3) / 4;
  // GCN layer 0: latent(64) -> y(B2) -> gather -> B4
  ngemm<64, 128, false, false><<<dim3(nblk), dim3(256), 0, stream>>>(latent, gW0T, nullptr, B2, n);
  gcn_gather<<<dim3(gblk), dim3(256), 0, stream>>>(B2, rowptr, cidx, enrm, dinv, gb0, B4, n);
  // GCN layer 1
  ngemm<128, 128, false, false><<<dim3(nblk), dim3(256), 0, stream>>>(B4, gW1T, nullptr, B2, n);
  gcn_gather<<<dim3(gblk), dim3(256), 0, stream>>>(B2, rowptr, cidx, enrm, dinv, gb1, B4, n);
  // GCN layer 2 -> xout
  ngemm<128, 128, false, false><<<dim3(nblk), dim3(256), 0, stream>>>(B4, gW2T, nullptr, B2, n);
  gcn_gather<<<dim3(gblk), dim3(256), 0, stream>>>(B2, rowptr, cidx, enrm, dinv, gb2, xout, n);

  // edge head precompute: P = x@W1_top, Q = x@W1_bot
  ngemm<128, 128, false, false><<<dim3(nblk), dim3(256), 0, stream>>>(xout, eW1tT, nullptr, B1, n);
  ngemm<128, 128, false, false><<<dim3(nblk), dim3(256), 0, stream>>>(xout, eW1bT, nullptr, B2, n);
  edge_head<<<dim3((ne + 63) / 64), dim3(256), 0, stream>>>(
      B1, B2, src, dst, eb1, eW2T, eb2, eW3, eb3, ep, ne, n);

  node_heads<<<dim3((n + 255) / 256), dim3(256), 0, stream>>>(
      xout, cW1T, cb1, cW2T, cb2, uW1T, ub1, uW2, ub2, cls, unc, n);
}

// Round 5
// 3503.070 us; speedup vs baseline: 5.8134x; 1.0050x over previous
//
#include <hip/hip_runtime.h>
#include <math.h>

typedef float f32x4 __attribute__((ext_vector_type(4)));
typedef short s16x8 __attribute__((ext_vector_type(8)));

// ---------------------------------------------------------------- helpers
__device__ __forceinline__ float sigmoid_(float x) { return 1.f / (1.f + __expf(-x)); }
__device__ __forceinline__ float tanh_(float x) {
  x = fminf(fmaxf(x, -30.f), 30.f);
  float e = __expf(2.f * x);
  return (e - 1.f) / (e + 1.f);
}
__device__ __forceinline__ float softplus_(float x) {
  return (x > 15.f) ? x : log1pf(__expf(x));
}
__device__ __forceinline__ unsigned short f2bf(float f) {  // RNE fp32->bf16
  unsigned u = __float_as_uint(f);
  u += 0x7fffu + ((u >> 16) & 1u);
  return (unsigned short)(u >> 16);
}

// Per-thread GEMM tile: node = lane (64 nodes/block), wave wq owns CPT columns.
template<int CPT, int LDA>
__device__ __forceinline__ void gemm_tile(float* acc, const float* A, int K,
                                          const float* WT, int ldw, int lane, int wq)
{
  for (int k0 = 0; k0 < K; k0 += 8) {
    float a[8];
#pragma unroll
    for (int i = 0; i < 8; ++i) a[i] = A[(k0 + i) * LDA + lane];
#pragma unroll
    for (int u = 0; u < CPT; ++u) {
      const float* wr = WT + (size_t)(wq * CPT + u) * ldw + k0;
#pragma unroll
      for (int i = 0; i < 8; ++i) acc[u] = fmaf(a[i], wr[i], acc[u]);
    }
  }
}

// ---------------------------------------------------------------- LSTM weight prep
__global__ void prep_lstm_w(const float* __restrict__ Wih0, const float* __restrict__ Whh0,
                            const float* __restrict__ Wih1, const float* __restrict__ Whh1,
                            const float* __restrict__ bih0, const float* __restrict__ bhh0,
                            const float* __restrict__ bih1, const float* __restrict__ bhh1,
                            unsigned short* __restrict__ Wp0, unsigned short* __restrict__ Wp1,
                            float* __restrict__ bs0, float* __restrict__ bs1)
{
  int idx = blockIdx.x * 256 + threadIdx.x;
  if (idx < 20 * 512 * 8) {
    int c = idx >> 12, rem = idx & 4095;
    int col = rem >> 3, e = rem & 7;
    int k = c * 8 + e;
    float v = 0.f;
    if (k < 16) v = Wih0[col * 16 + k];
    else if (k >= 32) v = Whh0[col * 128 + (k - 32)];
    Wp0[idx] = f2bf(v);
  }
  int i1 = idx - 20 * 512 * 8;
  if (i1 >= 0 && i1 < 32 * 512 * 8) {
    int c = i1 >> 12, rem = i1 & 4095;
    int col = rem >> 3, e = rem & 7;
    int k = c * 8 + e;
    float v = (k < 128) ? Wih1[col * 128 + k] : Whh1[col * 128 + (k - 128)];
    Wp1[i1] = f2bf(v);
  }
  int i2 = idx - 52 * 512 * 8;
  if (i2 >= 0 && i2 < 512) bs0[i2] = bih0[i2] + bhh0[i2];
  int i3 = i2 - 512;
  if (i3 >= 0 && i3 < 512) bs1[i3] = bih1[i3] + bhh1[i3];
}

// ---------------------------------------------------------------- LSTM epilogue (shared)
__device__ __forceinline__ void lstm_epi_m(const f32x4 (&acc)[4][4], f32x4 (&cs)[4],
    const float (&bs)[4], unsigned short* __restrict__ lds, int uoff, int kq,
    int nodebase, float* __restrict__ hf, int u, int n, bool last)
{
#pragma unroll
  for (int m = 0; m < 4; ++m) {
#pragma unroll
    for (int r = 0; r < 4; ++r) {
      float gi = acc[m][0][r] + bs[0];
      float gf = acc[m][1][r] + bs[1];
      float gg = acc[m][2][r] + bs[2];
      float go = acc[m][3][r] + bs[3];
      float c = sigmoid_(gf) * cs[m][r] + sigmoid_(gi) * tanh_(gg);
      cs[m][r] = c;
      float h = sigmoid_(go) * tanh_(c);
      int node = m * 16 + kq * 4 + r;
      lds[uoff + node * 8] = f2bf(h);
      if (last) {
        int gn = nodebase + node;
        if (gn < n) hf[(size_t)gn * 128 + u] = h;
      }
    }
  }
}

// ---------------------------------------------------------------- LSTM layer 0
__global__ __launch_bounds__(512, 2) void lstm_l0(
    const float* __restrict__ seq, const unsigned short* __restrict__ Wp0,
    const float* __restrict__ bs0, unsigned short* __restrict__ h0seq,
    int n, int tile0, int ntiles)
{
  __shared__ __align__(16) unsigned short A0[20 * 512];
  const int tid = threadIdx.x;
  const int l = tid & 63;
  const int wq = __builtin_amdgcn_readfirstlane(tid >> 6);
  const int kq = l >> 4;
  const int la = (l & 15) * 8;
  const int colu = wq * 16 + (l & 15);
  const int uoff = (4 + (colu >> 3)) * 512 + (colu & 7);

  s16x8 b0[5][4];
#pragma unroll
  for (int kc = 0; kc < 5; ++kc)
#pragma unroll
    for (int g = 0; g < 4; ++g)
      b0[kc][g] = *(const s16x8*)&Wp0[(size_t)(kc * 4 + kq) * 4096 + (g * 128 + colu) * 8];
  float bsr[4];
#pragma unroll
  for (int g = 0; g < 4; ++g) bsr[g] = bs0[g * 128 + colu];
  const f32x4 zero4 = {0.f, 0.f, 0.f, 0.f};

  for (int tt = blockIdx.x; tt < ntiles; tt += gridDim.x) {
    const int nodebase = (tile0 + tt) * 64;
    const int nld = min(nodebase + (tid >> 2), n - 1);
    unsigned short* __restrict__ hdst = h0seq + (size_t)tt * 20 * 8192;
    for (int i = tid; i < 18 * 512; i += 512) A0[2 * 512 + i] = 0;
    if (tid < 256) {
      int nd = tid >> 2, q = tid & 3;
      float4 v = *(const float4*)(seq + (size_t)nld * 320 + q * 4);
      unsigned d0 = (unsigned)f2bf(v.x) | ((unsigned)f2bf(v.y) << 16);
      unsigned d1 = (unsigned)f2bf(v.z) | ((unsigned)f2bf(v.w) << 16);
      unsigned* dstp = (unsigned*)&A0[(q >> 1) * 512 + nd * 8 + (q & 1) * 4];
      dstp[0] = d0; dstp[1] = d1;
    }
    f32x4 c0[4];
#pragma unroll
    for (int m = 0; m < 4; ++m) c0[m] = zero4;
    __syncthreads();

    for (int t = 0; t < 20; ++t) {
      float4 xnext;
      const bool ldx = (t < 19) && (tid < 256);
      if (ldx) xnext = *(const float4*)(seq + (size_t)nld * 320 + (t + 1) * 16 + (tid & 3) * 4);

      f32x4 acc[4][4];
#pragma unroll
      for (int m = 0; m < 4; ++m)
#pragma unroll
        for (int g = 0; g < 4; ++g) acc[m][g] = zero4;
#pragma unroll
      for (int kc = 0; kc < 5; ++kc) {
        s16x8 av[4];
#pragma unroll
        for (int m = 0; m < 4; ++m)
          av[m] = *(const s16x8*)&A0[(kc * 4 + kq) * 512 + m * 128 + la];
#pragma unroll
        for (int g = 0; g < 4; ++g)
#pragma unroll
          for (int m = 0; m < 4; ++m)
            acc[m][g] = __builtin_amdgcn_mfma_f32_16x16x32_bf16(av[m], b0[kc][g], acc[m][g], 0, 0, 0);
      }
      __syncthreads();                 // MFMA reads of A0 done
      lstm_epi_m(acc, c0, bsr, A0, uoff, kq, 0, nullptr, colu, 0, false);
      if (ldx) {
        int nd = tid >> 2, q = tid & 3;
        unsigned d0 = (unsigned)f2bf(xnext.x) | ((unsigned)f2bf(xnext.y) << 16);
        unsigned d1 = (unsigned)f2bf(xnext.z) | ((unsigned)f2bf(xnext.w) << 16);
        unsigned* dstp = (unsigned*)&A0[(q >> 1) * 512 + nd * 8 + (q & 1) * 4];
        dstp[0] = d0; dstp[1] = d1;
      }
      __syncthreads();                 // h0(t) + x(t+1) visible
      {
        s16x8 u0 = *(const s16x8*)&A0[2048 + tid * 8];
        s16x8 u1 = *(const s16x8*)&A0[2048 + 4096 + tid * 8];
        *(s16x8*)&hdst[(size_t)t * 8192 + tid * 8] = u0;
        *(s16x8*)&hdst[(size_t)t * 8192 + 4096 + tid * 8] = u1;
      }
    }
  }
}

// ---------------------------------------------------------------- LSTM layer 1
__global__ __launch_bounds__(512, 2) void lstm_l1(
    const unsigned short* __restrict__ h0seq, const unsigned short* __restrict__ Wp1,
    const float* __restrict__ bs1, float* __restrict__ hfinal,
    int n, int tile0, int ntiles)
{
  __shared__ __align__(16) unsigned short A1[48 * 512];  // 0..15 h0 buf0, 16..31 h0 buf1, 32..47 h1
  const int tid = threadIdx.x;
  const int l = tid & 63;
  const int wq = __builtin_amdgcn_readfirstlane(tid >> 6);
  const int kq = l >> 4;
  const int la = (l & 15) * 8;
  const int colu = wq * 16 + (l & 15);
  const int uoff = (32 + (colu >> 3)) * 512 + (colu & 7);

  s16x8 b1[8][4];
#pragma unroll
  for (int kc = 0; kc < 8; ++kc)
#pragma unroll
    for (int g = 0; g < 4; ++g)
      b1[kc][g] = *(const s16x8*)&Wp1[(size_t)(kc * 4 + kq) * 4096 + (g * 128 + colu) * 8];
  float bsr[4];
#pragma unroll
  for (int g = 0; g < 4; ++g) bsr[g] = bs1[g * 128 + colu];
  const f32x4 zero4 = {0.f, 0.f, 0.f, 0.f};

  for (int tt = blockIdx.x; tt < ntiles; tt += gridDim.x) {
    const int nodebase = (tile0 + tt) * 64;
    const unsigned short* __restrict__ hsrc = h0seq + (size_t)tt * 20 * 8192;
    for (int i = tid; i < 16 * 512; i += 512) A1[32 * 512 + i] = 0;
    {  // stage h0(0) -> buf0
      s16x8 s0 = *(const s16x8*)&hsrc[tid * 8];
      s16x8 s1 = *(const s16x8*)&hsrc[4096 + tid * 8];
      *(s16x8*)&A1[tid * 8] = s0;
      *(s16x8*)&A1[4096 + tid * 8] = s1;
    }
    f32x4 c1[4];
#pragma unroll
    for (int m = 0; m < 4; ++m) c1[m] = zero4;
    __syncthreads();

    for (int t = 0; t < 20; ++t) {
      s16x8 p0, p1;
      const bool ld = (t < 19);
      if (ld) {
        p0 = *(const s16x8*)&hsrc[(size_t)(t + 1) * 8192 + tid * 8];
        p1 = *(const s16x8*)&hsrc[(size_t)(t + 1) * 8192 + 4096 + tid * 8];
      }
      const int hb = (t & 1) * 16;
      f32x4 acc[4][4];
#pragma unroll
      for (int m = 0; m < 4; ++m)
#pragma unroll
        for (int g = 0; g < 4; ++g) acc[m][g] = zero4;
#pragma unroll
      for (int kc = 0; kc < 8; ++kc) {
        const int ch = (kc < 4) ? (hb + kc * 4 + kq) : (32 + (kc - 4) * 4 + kq);
        s16x8 av[4];
#pragma unroll
        for (int m = 0; m < 4; ++m)
          av[m] = *(const s16x8*)&A1[ch * 512 + m * 128 + la];
#pragma unroll
        for (int g = 0; g < 4; ++g)
#pragma unroll
          for (int m = 0; m < 4; ++m)
            acc[m][g] = __builtin_amdgcn_mfma_f32_16x16x32_bf16(av[m], b1[kc][g], acc[m][g], 0, 0, 0);
      }
      __syncthreads();                 // MFMA reads done
      lstm_epi_m(acc, c1, bsr, A1, uoff, kq, nodebase, hfinal, colu, n, t == 19);
      if (ld) {
        const int ob = ((t + 1) & 1) * 16 * 512;
        *(s16x8*)&A1[ob + tid * 8] = p0;
        *(s16x8*)&A1[ob + 4096 + tid * 8] = p1;
      }
      __syncthreads();                 // h1(t) + h0(t+1) visible
    }
  }
}

// ---------------------------------------------------------------- LSTM fused fallback (small ws)
__global__ __launch_bounds__(512, 1) void lstm_reg(
    const float* __restrict__ seq,
    const unsigned short* __restrict__ Wp0, const unsigned short* __restrict__ Wp1,
    const float* __restrict__ bs0, const float* __restrict__ bs1,
    float* __restrict__ hfinal, int n, int ntiles)
{
  __shared__ __align__(16) unsigned short Abuf[36 * 512];
  const int tid = threadIdx.x;
  const int l = tid & 63;
  const int wq = __builtin_amdgcn_readfirstlane(tid >> 6);
  const int kq = l >> 4;
  const int la = (l & 15) * 8;
  const int colu = wq * 16 + (l & 15);
  const int uoff0 = (4 + (colu >> 3)) * 512 + (colu & 7);
  const int uoff1 = (20 + (colu >> 3)) * 512 + (colu & 7);

  float bsr0[4], bsr1[4];
#pragma unroll
  for (int g = 0; g < 4; ++g) {
    bsr0[g] = bs0[g * 128 + colu];
    bsr1[g] = bs1[g * 128 + colu];
  }
  const f32x4 zero4 = {0.f, 0.f, 0.f, 0.f};

  for (int tile = blockIdx.x; tile < ntiles; tile += gridDim.x) {
    const int nodebase = tile * 64;
    const int nld = min(nodebase + (tid >> 2), n - 1);
    for (int i = tid; i < 34 * 512; i += 512) Abuf[2 * 512 + i] = 0;
    if (tid < 256) {
      int nd = tid >> 2, q = tid & 3;
      float4 v = *(const float4*)(seq + (size_t)nld * 320 + q * 4);
      unsigned d0 = (unsigned)f2bf(v.x) | ((unsigned)f2bf(v.y) << 16);
      unsigned d1 = (unsigned)f2bf(v.z) | ((unsigned)f2bf(v.w) << 16);
      unsigned* dst = (unsigned*)&Abuf[(q >> 1) * 512 + nd * 8 + (q & 1) * 4];
      dst[0] = d0; dst[1] = d1;
    }
    f32x4 c0[4], c1[4];
#pragma unroll
    for (int m = 0; m < 4; ++m) { c0[m] = zero4; c1[m] = zero4; }
    __syncthreads();

    for (int t = 0; t < 20; ++t) {
      float4 xnext;
      const bool ldx = (t < 19) && (tid < 256);
      if (ldx) xnext = *(const float4*)(seq + (size_t)nld * 320 + (t + 1) * 16 + (tid & 3) * 4);

      f32x4 acc[4][4];
#pragma unroll
      for (int m = 0; m < 4; ++m)
#pragma unroll
        for (int g = 0; g < 4; ++g) acc[m][g] = zero4;
#pragma unroll
      for (int kc = 0; kc < 5; ++kc) {
        s16x8 av[4];
#pragma unroll
        for (int m = 0; m < 4; ++m)
          av[m] = *(const s16x8*)&Abuf[(kc * 4 + kq) * 512 + m * 128 + la];
#pragma unroll
        for (int g = 0; g < 4; ++g) {
          s16x8 bv = *(const s16x8*)&Wp0[(size_t)(kc * 4 + kq) * 4096 + (g * 128 + colu) * 8];
#pragma unroll
          for (int m = 0; m < 4; ++m)
            acc[m][g] = __builtin_amdgcn_mfma_f32_16x16x32_bf16(av[m], bv, acc[m][g], 0, 0, 0);
        }
      }
      __syncthreads();
      lstm_epi_m(acc, c0, bsr0, Abuf, uoff0, kq, nodebase, hfinal, colu, n, false);
      if (ldx) {
        int nd = tid >> 2, q = tid & 3;
        unsigned d0 = (unsigned)f2bf(xnext.x) | ((unsigned)f2bf(xnext.y) << 16);
        unsigned d1 = (unsigned)f2bf(xnext.z) | ((unsigned)f2bf(xnext.w) << 16);
        unsigned* dst = (unsigned*)&Abuf[(q >> 1) * 512 + nd * 8 + (q & 1) * 4];
        dst[0] = d0; dst[1] = d1;
      }
      __syncthreads();

#pragma unroll
      for (int m = 0; m < 4; ++m)
#pragma unroll
        for (int g = 0; g < 4; ++g) acc[m][g] = zero4;
#pragma unroll
      for (int kc = 0; kc < 8; ++kc) {
        s16x8 av[4];
#pragma unroll
        for (int m = 0; m < 4; ++m)
          av[m] = *(const s16x8*)&Abuf[(4 + kc * 4 + kq) * 512 + m * 128 + la];
#pragma unroll
        for (int g = 0; g < 4; ++g) {
          s16x8 bv = *(const s16x8*)&Wp1[(size_t)(kc * 4 + kq) * 4096 + (g * 128 + colu) * 8];
#pragma unroll
          for (int m = 0; m < 4; ++m)
            acc[m][g] = __builtin_amdgcn_mfma_f32_16x16x32_bf16(av[m], bv, acc[m][g], 0, 0, 0);
        }
      }
      __syncthreads();
      lstm_epi_m(acc, c1, bsr1, Abuf, uoff1, kq, nodebase, hfinal, colu, n, t == 19);
      __syncthreads();
    }
  }
}

// ---------------------------------------------------------------- generic node GEMM
template<int KDIM, int COLS, bool RELU, bool BIAS>
__global__ __launch_bounds__(256, 4) void ngemm(
    const float* __restrict__ xin, const float* __restrict__ WT,
    const float* __restrict__ b, float* __restrict__ out, int n)
{
  __shared__ float A[KDIM][65];
  const int lane = threadIdx.x & 63;
  const int wq = __builtin_amdgcn_readfirstlane(threadIdx.x >> 6);
  const int node = blockIdx.x * 64 + lane;

  for (int i = threadIdx.x; i < 64 * KDIM; i += 256) {
    int nn = i / KDIM, k = i % KDIM;
    int g = min(blockIdx.x * 64 + nn, n - 1);
    A[k][nn] = xin[(size_t)g * KDIM + k];
  }
  __syncthreads();

  constexpr int CPT = COLS / 4;
  float acc[CPT];
#pragma unroll
  for (int u = 0; u < CPT; ++u) acc[u] = 0.f;
  gemm_tile<CPT, 65>(acc, &A[0][0], KDIM, WT, KDIM, lane, wq);

  if (node < n) {
#pragma unroll
    for (int u = 0; u < CPT; ++u) {
      int col = wq * CPT + u;
      float v = acc[u];
      if (BIAS) v += b[col];
      if (RELU) v = fmaxf(v, 0.f);
      out[(size_t)node * COLS + col] = v;
    }
  }
}

// ---------------------------------------------------------------- small utility kernels
__global__ void transpose_k(const float* __restrict__ s, float* __restrict__ d, int R, int C) {
  int i = blockIdx.x * 256 + threadIdx.x;
  if (i < R * C) { int r = i / C, c = i % C; d[(size_t)c * R + r] = s[i]; }
}

__global__ void deg_count(const int* __restrict__ dst, float* __restrict__ deg, int ne, int n) {
  int i = blockIdx.x * 256 + threadIdx.x;
  if (i < ne) {
    int d = dst[i]; d = min(max(d, 0), n - 1);
    atomicAdd(deg + d, 1.f);
  }
}

__global__ void dinv_k(const float* __restrict__ deg, float* __restrict__ dinv, int n) {
  int i = blockIdx.x * 256 + threadIdx.x;
  if (i < n) dinv[i] = rsqrtf(deg[i] + 1.f);   // +1 self-loop
}

// exclusive prefix sum of (int)deg -> rowptr[0..n]
__global__ void scan_k(const float* __restrict__ deg, int* __restrict__ rowptr, int n) {
  __shared__ int sh[1024];
  __shared__ int carry;
  const int tid = threadIdx.x;
  if (tid == 0) carry = 0;
  __syncthreads();
  for (int base = 0; base < n; base += 1024) {
    int i = base + tid;
    int v = (i < n) ? (int)deg[i] : 0;
    sh[tid] = v;
    __syncthreads();
    for (int off = 1; off < 1024; off <<= 1) {
      int t = (tid >= off) ? sh[tid - off] : 0;
      __syncthreads();
      sh[tid] += t;
      __syncthreads();
    }
    if (i < n) rowptr[i] = carry + sh[tid] - v;
    int tot = sh[1023];
    __syncthreads();
    if (tid == 0) carry += tot;
    __syncthreads();
  }
  if (tid == 0) rowptr[n] = carry;
}

__global__ void fill_k(const int* __restrict__ src, const int* __restrict__ dst,
                       const int* __restrict__ rowptr, int* __restrict__ cursor,
                       const float* __restrict__ dinv,
                       int* __restrict__ cidx, float* __restrict__ enrm, int ne, int n) {
  int i = blockIdx.x * 256 + threadIdx.x;
  if (i < ne) {
    int s = min(max(src[i], 0), n - 1);
    int d = min(max(dst[i], 0), n - 1);
    int p = atomicAdd(cursor + d, 1);
    int o = rowptr[d] + p;
    cidx[o] = s;
    enrm[o] = dinv[s] * dinv[d];
  }
}

// fused: out = relu( dinv[d]^2*y[d] + sum_e enrm*y[src] + b ), one wave per node
__global__ __launch_bounds__(256, 4) void gcn_gather(
    const float* __restrict__ y, const int* __restrict__ rowptr,
    const int* __restrict__ cidx, const float* __restrict__ enrm,
    const float* __restrict__ dinv, const float* __restrict__ b,
    float* __restrict__ out, int n)
{
  const int l = threadIdx.x & 63;
  const int wq = threadIdx.x >> 6;
  const int node = blockIdx.x * 4 + wq;
  if (node >= n) return;
  float dv = dinv[node];
  float2 acc = *(const float2*)(y + (size_t)node * 128 + l * 2);
  acc.x *= dv * dv; acc.y *= dv * dv;
  int r0 = rowptr[node], r1 = rowptr[node + 1];
  int e = r0;
  for (; e + 1 < r1; e += 2) {
    int s0 = cidx[e], s1 = cidx[e + 1];
    float n0 = enrm[e], n1 = enrm[e + 1];
    float2 v0 = *(const float2*)(y + (size_t)s0 * 128 + l * 2);
    float2 v1 = *(const float2*)(y + (size_t)s1 * 128 + l * 2);
    acc.x = fmaf(n0, v0.x, acc.x); acc.y = fmaf(n0, v0.y, acc.y);
    acc.x = fmaf(n1, v1.x, acc.x); acc.y = fmaf(n1, v1.y, acc.y);
  }
  if (e < r1) {
    int s0 = cidx[e];
    float n0 = enrm[e];
    float2 v0 = *(const float2*)(y + (size_t)s0 * 128 + l * 2);
    acc.x = fmaf(n0, v0.x, acc.x); acc.y = fmaf(n0, v0.y, acc.y);
  }
  float2 bb = *(const float2*)(b + l * 2);
  float2 o;
  o.x = fmaxf(acc.x + bb.x, 0.f);
  o.y = fmaxf(acc.y + bb.y, 0.f);
  *(float2*)(out + (size_t)node * 128 + l * 2) = o;
}

// ---------------------------------------------------------------- heads
__global__ __launch_bounds__(256, 2) void node_heads(
    const float* __restrict__ x,
    const float* __restrict__ cW1T, const float* __restrict__ cb1,
    const float* __restrict__ cW2T, const float* __restrict__ cb2,
    const float* __restrict__ uW1T, const float* __restrict__ ub1,
    const float* __restrict__ uW2,  const float* __restrict__ ub2,
    float* __restrict__ cls, float* __restrict__ unc, int n)
{
  int node = blockIdx.x * 256 + threadIdx.x;
  int nld = min(node, n - 1);
  const float* xp = x + (size_t)nld * 128;
  float hc[64], hu[64];
#pragma unroll
  for (int j = 0; j < 64; ++j) { hc[j] = cb1[j]; hu[j] = ub1[j]; }
  for (int k0 = 0; k0 < 128; k0 += 8) {
    float xk[8];
    *(float4*)&xk[0] = *(const float4*)(xp + k0);
    *(float4*)&xk[4] = *(const float4*)(xp + k0 + 4);
#pragma unroll
    for (int j = 0; j < 64; ++j) {
      const float* cw = cW1T + (size_t)j * 128 + k0;
      const float* uw = uW1T + (size_t)j * 128 + k0;
#pragma unroll
      for (int i = 0; i < 8; ++i) {
        hc[j] = fmaf(xk[i], cw[i], hc[j]);
        hu[j] = fmaf(xk[i], uw[i], hu[j]);
      }
    }
  }
  float vc0 = cb2[0], vc1 = cb2[1], vc2 = cb2[2], vc3 = cb2[3];
  float ua = ub2[0];
#pragma unroll
  for (int j = 0; j < 64; ++j) {
    float hcr = fmaxf(hc[j], 0.f), hur = fmaxf(hu[j], 0.f);
    vc0 = fmaf(hcr, cW2T[0 * 64 + j], vc0);
    vc1 = fmaf(hcr, cW2T[1 * 64 + j], vc1);
    vc2 = fmaf(hcr, cW2T[2 * 64 + j], vc2);
    vc3 = fmaf(hcr, cW2T[3 * 64 + j], vc3);
    ua  = fmaf(hur, uW2[j], ua);
  }
  if (node < n) {
    float4 vo; vo.x = vc0; vo.y = vc1; vo.z = vc2; vo.w = vc3;
    *(float4*)(cls + (size_t)node * 4) = vo;
    unc[node] = softplus_(ua);
  }
}

__global__ __launch_bounds__(256, 2) void edge_head(
    const float* __restrict__ P, const float* __restrict__ Q,
    const int* __restrict__ src, const int* __restrict__ dst,
    const float* __restrict__ b1,
    const float* __restrict__ eW2T, const float* __restrict__ b2,
    const float* __restrict__ eW3, const float* __restrict__ b3,
    float* __restrict__ ep, int ne, int n)
{
  __shared__ float H1[128][66];
  __shared__ float H2[64][64];
  const int lane = threadIdx.x & 63;
  const int wq = __builtin_amdgcn_readfirstlane(threadIdx.x >> 6);
  const int e0 = blockIdx.x * 64;
  {
    int el = threadIdx.x >> 2, q = threadIdx.x & 3;
    int e = min(e0 + el, ne - 1);
    int s = min(max(src[e], 0), n - 1);
    int d = min(max(dst[e], 0), n - 1);
    const float* pr = P + (size_t)s * 128 + q * 32;
    const float* qr = Q + (size_t)d * 128 + q * 32;
#pragma unroll
    for (int i = 0; i < 32; i += 4) {
      float4 a = *(const float4*)(pr + i);
      float4 c = *(const float4*)(qr + i);
      int jb = q * 32 + i;
      H1[jb + 0][el] = fmaxf(a.x + c.x + b1[jb + 0], 0.f);
      H1[jb + 1][el] = fmaxf(a.y + c.y + b1[jb + 1], 0.f);
      H1[jb + 2][el] = fmaxf(a.z + c.z + b1[jb + 2], 0.f);
      H1[jb + 3][el] = fmaxf(a.w + c.w + b1[jb + 3], 0.f);
    }
  }
  __syncthreads();
  float acc[16];
#pragma unroll
  for (int u = 0; u < 16; ++u) acc[u] = 0.f;
  gemm_tile<16, 66>(acc, &H1[0][0], 128, eW2T, 128, lane, wq);
#pragma unroll
  for (int u = 0; u < 16; ++u) {
    int col = wq * 16 + u;
    H2[col][lane] = fmaxf(acc[u] + b2[col], 0.f);
  }
  __syncthreads();
  if (wq == 0) {
    float a3 = b3[0];
    for (int k = 0; k < 64; ++k) a3 = fmaf(H2[k][lane], eW3[k], a3);
    int e = e0 + lane;
    if (e < ne) ep[e] = 1.f / (1.f + __expf(-a3));
  }
}

// ---------------------------------------------------------------- host
extern "C" void kernel_launch(void* const* d_in, const int* in_sizes, int n_in,
                              void* d_out, int out_size, void* d_ws, size_t ws_size,
                              hipStream_t stream)
{
  const float* seq   = (const float*)d_in[0];
  const int*   eidx  = (const int*)d_in[1];
  const float* Wih0  = (const float*)d_in[2];
  const float* Whh0  = (const float*)d_in[3];
  const float* bih0  = (const float*)d_in[4];
  const float* bhh0  = (const float*)d_in[5];
  const float* Wih1  = (const float*)d_in[6];
  const float* Whh1  = (const float*)d_in[7];
  const float* bih1  = (const float*)d_in[8];
  const float* bhh1  = (const float*)d_in[9];
  const float* encW1 = (const float*)d_in[10];
  const float* encb1 = (const float*)d_in[11];
  const float* encW2 = (const float*)d_in[12];
  const float* encb2 = (const float*)d_in[13];
  const float* gW0   = (const float*)d_in[14];
  const float* gb0   = (const float*)d_in[15];
  const float* gW1   = (const float*)d_in[16];
  const float* gb1   = (const float*)d_in[17];
  const float* gW2   = (const float*)d_in[18];
  const float* gb2   = (const float*)d_in[19];
  const float* eW1   = (const float*)d_in[20];
  const float* eb1   = (const float*)d_in[21];
  const float* eW2   = (const float*)d_in[22];
  const float* eb2   = (const float*)d_in[23];
  const float* eW3   = (const float*)d_in[24];
  const float* eb3   = (const float*)d_in[25];
  const float* cW1   = (const float*)d_in[26];
  const float* cb1   = (const float*)d_in[27];
  const float* cW2   = (const float*)d_in[28];
  const float* cb2   = (const float*)d_in[29];
  const float* uW1   = (const float*)d_in[30];
  const float* ub1   = (const float*)d_in[31];
  const float* uW2   = (const float*)d_in[32];
  const float* ub2   = (const float*)d_in[33];

  const int n  = in_sizes[0] / 320;     // 50000
  const int ne = in_sizes[1] / 2;       // 800000
  const int* src = eidx;
  const int* dst = eidx + ne;

  char* ws = (char*)d_ws;
  size_t off = 0;
  auto alloc = [&](size_t elems) -> float* {
    float* p = (float*)(ws + off);
    off += ((elems * 4 + 255) & ~(size_t)255);
    return p;
  };
  const size_t nb = (size_t)n * 128;
  float* B1     = alloc(nb);        // hf, later P
  float* B2     = alloc(nb);        // y / Q
  float* B4     = alloc(nb);        // x (gcn activations)
  float* latent = alloc((size_t)n * 64);
  float* deg    = alloc(n);
  float* dinv   = alloc(n);
  int*   rowptr = (int*)alloc(n + 1);
  int*   cursor = (int*)alloc(n);
  int*   cidx   = (int*)alloc(ne);
  float* enrm   = alloc(ne);
  float* encW1T = alloc(128 * 128);
  float* encW2T = alloc(64 * 128);
  float* gW0T   = alloc(128 * 64);
  float* gW1T   = alloc(128 * 128);
  float* gW2T   = alloc(128 * 128);
  float* eW1tT  = alloc(128 * 128);
  float* eW1bT  = alloc(128 * 128);
  float* eW2T   = alloc(64 * 128);
  float* cW1T   = alloc(64 * 128);
  float* cW2T   = alloc(4 * 64);
  float* uW1T   = alloc(64 * 128);
  unsigned short* Wp0 = (unsigned short*)alloc(20 * 512 * 8 / 2);
  unsigned short* Wp1 = (unsigned short*)alloc(32 * 512 * 8 / 2);
  float* bsum0  = alloc(512);
  float* bsum1  = alloc(512);
  (void)n_in; (void)out_size;

  float* xout = (float*)d_out;                    // [n][128]
  float* ep   = xout + nb;                        // [ne]
  float* cls  = ep + ne;                          // [n][4]
  float* unc  = cls + (size_t)n * 4;              // [n]

  auto T = [&](const float* s, float* d, int R, int C) {
    transpose_k<<<dim3((R * C + 255) / 256), dim3(256), 0, stream>>>(s, d, R, C);
  };
  T(encW1, encW1T, 128, 128);
  T(encW2, encW2T, 128, 64);
  T(gW0,   gW0T,   64, 128);
  T(gW1,   gW1T,   128, 128);
  T(gW2,   gW2T,   128, 128);
  T(eW1,            eW1tT, 128, 128);
  T(eW1 + 128*128,  eW1bT, 128, 128);
  T(eW2,   eW2T,   128, 64);
  T(cW1,   cW1T,   128, 64);
  T(cW2,   cW2T,   64, 4);
  T(uW1,   uW1T,   128, 64);

  prep_lstm_w<<<dim3((52 * 512 * 8 + 1024 + 255) / 256), dim3(256), 0, stream>>>(
      Wih0, Whh0, Wih1, Whh1, bih0, bhh0, bih1, bhh1, Wp0, Wp1, bsum0, bsum1);

  // ---- CSR build (once) ----
  hipMemsetAsync(deg, 0, (size_t)n * 4, stream);
  deg_count<<<dim3((ne + 255) / 256), dim3(256), 0, stream>>>(dst, deg, ne, n);
  dinv_k<<<dim3((n + 255) / 256), dim3(256), 0, stream>>>(deg, dinv, n);
  scan_k<<<dim3(1), dim3(1024), 0, stream>>>(deg, rowptr, n);
  hipMemsetAsync(cursor, 0, (size_t)n * 4, stream);
  fill_k<<<dim3((ne + 255) / 256), dim3(256), 0, stream>>>(
      src, dst, rowptr, cursor, dinv, cidx, enrm, ne, n);

  const int nblk = (n + 63) / 64;
  const int ntiles = nblk;

  // ---- LSTM: layer-split, 2 blocks/CU (grid 512) ----
  const size_t per_tile = (size_t)20 * 8192 * sizeof(unsigned short);   // 320 KB
  size_t avail = (ws_size > off) ? (ws_size - off) : 0;
  int slab_tiles = (int)((avail / per_tile < (size_t)ntiles) ? (avail / per_tile) : (size_t)ntiles);
  if (slab_tiles >= 8) {
    unsigned short* h0seq = (unsigned short*)(ws + off);
    for (int t0 = 0; t0 < ntiles; t0 += slab_tiles) {
      int st = (ntiles - t0 < slab_tiles) ? (ntiles - t0) : slab_tiles;
      int grid = (st < 512) ? st : 512;
      lstm_l0<<<dim3(grid), dim3(512), 0, stream>>>(seq, Wp0, bsum0, h0seq, n, t0, st);
      lstm_l1<<<dim3(grid), dim3(512), 0, stream>>>(h0seq, Wp1, bsum1, B1, n, t0, st);
    }
  } else {
    lstm_reg<<<dim3(256), dim3(512), 0, stream>>>(seq, Wp0, Wp1, bsum0, bsum1, B1, n, ntiles);
  }

  // encoder: B1 -> B2 -> latent
  ngemm<128, 128, true,  true ><<<dim3(nblk), dim3(256), 0, stream>>>(B1, encW1T, encb1, B2, n);
  ngemm<128, 64,  false, true ><<<dim3(nblk), dim3(256), 0, stream>>>(B2, encW2T, encb2, latent, n);

  const int gblk = (n + 3) / 4;
  // GCN layer 0: latent(64) -> y(B2) -> gather -> B4
  ngemm<64, 128, false, false><<<dim3(nblk), dim3(256), 0, stream>>>(latent, gW0T, nullptr, B2, n);
  gcn_gather<<<dim3(gblk), dim3(256), 0, stream>>>(B2, rowptr, cidx, enrm, dinv, gb0, B4, n);
  // GCN layer 1
  ngemm<128, 128, false, false><<<dim3(nblk), dim3(256), 0, stream>>>(B4, gW1T, nullptr, B2, n);
  gcn_gather<<<dim3(gblk), dim3(256), 0, stream>>>(B2, rowptr, cidx, enrm, dinv, gb1, B4, n);
  // GCN layer 2 -> xout
  ngemm<128, 128, false, false><<<dim3(nblk), dim3(256), 0, stream>>>(B4, gW2T, nullptr, B2, n);
  gcn_gather<<<dim3(gblk), dim3(256), 0, stream>>>(B2, rowptr, cidx, enrm, dinv, gb2, xout, n);

  // edge head precompute: P = x@W1_top, Q = x@W1_bot
  ngemm<128, 128, false, false><<<dim3(nblk), dim3(256), 0, stream>>>(xout, eW1tT, nullptr, B1, n);
  ngemm<128, 128, false, false><<<dim3(nblk), dim3(256), 0, stream>>>(xout, eW1bT, nullptr, B2, n);
  edge_head<<<dim3((ne + 63) / 64), dim3(256), 0, stream>>>(
      B1, B2, src, dst, eb1, eW2T, eb2, eW3, eb3, ep, ne, n);

  node_heads<<<dim3((n + 255) / 256), dim3(256), 0, stream>>>(
      xout, cW1T, cb1, cW2T, cb2, uW1T, ub1, uW2, ub2, cls, unc, n);
}